// Round 12
// baseline (316.894 us; speedup 1.0000x reference)
//
#include <hip/hip_runtime.h>

typedef unsigned short ushort_t;
typedef unsigned short us4 __attribute__((ext_vector_type(4)));
typedef unsigned short us8 __attribute__((ext_vector_type(8)));
typedef unsigned int   u32x4 __attribute__((ext_vector_type(4)));
typedef float          f32x4 __attribute__((ext_vector_type(4)));
typedef __bf16         bf16x8 __attribute__((ext_vector_type(8)));

__device__ __forceinline__ unsigned short f2bf(float f) {
  unsigned u = __builtin_bit_cast(unsigned, f);
  u += 0x7fffu + ((u >> 16) & 1u);
  return (unsigned short)(u >> 16);
}
__device__ __forceinline__ float bf2f(unsigned short h) {
  unsigned u = ((unsigned)h) << 16;
  return __builtin_bit_cast(float, u);
}

// async 16B global -> LDS (wave-uniform LDS base + lane*16; lane-linear here)
__device__ __forceinline__ void async_cp16(const ushort_t* g, ushort_t* l) {
  __builtin_amdgcn_global_load_lds(
      (const __attribute__((address_space(1))) unsigned int*)g,
      (__attribute__((address_space(3))) unsigned int*)l, 16, 0, 0);
}

// DPP row-rotate (16-lane row) — VALU-pipe cross-lane, replaces ds_bpermute
template <int CTRL>
__device__ __forceinline__ float dpp_rotf(float x) {
  return __builtin_bit_cast(float,
      __builtin_amdgcn_update_dpp(0, __builtin_bit_cast(int, x), CTRL, 0xF, 0xF, true));
}
// 16-lane reduction via row_ror 1,2,4,8 (covers all 16 lanes, any commutative op)
__device__ __forceinline__ float row16_max(float x) {
  x = fmaxf(x, dpp_rotf<0x121>(x));
  x = fmaxf(x, dpp_rotf<0x122>(x));
  x = fmaxf(x, dpp_rotf<0x124>(x));
  x = fmaxf(x, dpp_rotf<0x128>(x));
  return x;
}
__device__ __forceinline__ float row16_sum(float x) {
  x += dpp_rotf<0x121>(x);
  x += dpp_rotf<0x122>(x);
  x += dpp_rotf<0x124>(x);
  x += dpp_rotf<0x128>(x);
  return x;
}

// ---------------- prep kernels ----------------

__global__ __launch_bounds__(256) void k_conv_x(const float* __restrict__ in,
                                                ushort_t* __restrict__ out) {
  int i = (blockIdx.x * 256 + threadIdx.x) * 4;
  float4 v = *(const float4*)(in + i);
  us4 o;
  o[0] = f2bf(v.x); o[1] = f2bf(v.y); o[2] = f2bf(v.z); o[3] = f2bf(v.w);
  *(us4*)(out + i) = o;
}

// in[R][C] f32 -> out[C][R] bf16
__global__ __launch_bounds__(256) void k_transpose_bf16(const float* __restrict__ in,
                                                        ushort_t* __restrict__ out,
                                                        int R, int C) {
  __shared__ float tile[32][33];
  int c0 = blockIdx.x * 32, r0 = blockIdx.y * 32;
  int tx = threadIdx.x, ty = threadIdx.y;
#pragma unroll
  for (int k = 0; k < 32; k += 8)
    tile[ty + k][tx] = in[(size_t)(r0 + ty + k) * C + c0 + tx];
  __syncthreads();
#pragma unroll
  for (int k = 0; k < 32; k += 8)
    out[(size_t)(c0 + ty + k) * R + r0 + tx] = f2bf(tile[tx][ty + k]);
}

// r_emb (r, h, d) f32 -> RE16 [h][r][d] bf16
__global__ __launch_bounds__(256) void k_conv_remb(const float* __restrict__ re,
                                                   ushort_t* __restrict__ out) {
  int tid = blockIdx.x * 256 + threadIdx.x;
  int o = tid * 8;
  int d = o & 63, r = (o >> 6) & 2047, h = o >> 17;
  const float* src = re + ((size_t)r * 16 + h) * 64 + d;
  float4 a = *(const float4*)(src);
  float4 b = *(const float4*)(src + 4);
  us8 u;
  u[0] = f2bf(a.x); u[1] = f2bf(a.y); u[2] = f2bf(a.z); u[3] = f2bf(a.w);
  u[4] = f2bf(b.x); u[5] = f2bf(b.y); u[6] = f2bf(b.z); u[7] = f2bf(b.w);
  *(us8*)(out + o) = u;
}

// rbias2[h][r] = (r_bias[r][h] - dot(r_w_bias[h], r_emb_bf16[h][r])) * SCALE
__global__ __launch_bounds__(256) void k_rbias2(const ushort_t* __restrict__ RE,
                                                const float* __restrict__ rwb,
                                                const float* __restrict__ rbias,
                                                float* __restrict__ out) {
  int tid = blockIdx.x * 256 + threadIdx.x;  // 32768 total
  int h = tid >> 11, r = tid & 2047;
  const ushort_t* re = RE + ((size_t)h * 2048 + r) * 64;
  const float* wv = rwb + h * 64;
  float acc = 0.f;
#pragma unroll
  for (int d0 = 0; d0 < 64; d0 += 8) {
    us8 v = *(const us8*)(re + d0);
#pragma unroll
    for (int e = 0; e < 8; ++e) acc += bf2f(v[e]) * wv[d0 + e];
  }
  out[h * 2048 + r] = (rbias[r * 16 + h] - acc) * 0.125f;
}

// ---------------- GEMM 1: X(4096x1024) @ Wqkv -> scatter q~,k,v^T ----------------

__global__ __launch_bounds__(256) void k_gemm_qkv(const ushort_t* __restrict__ A,
                                                  const ushort_t* __restrict__ B,
                                                  const float* __restrict__ rwb,
                                                  ushort_t* __restrict__ qt,
                                                  ushort_t* __restrict__ kk,
                                                  ushort_t* __restrict__ vv) {
  __shared__ ushort_t Al[128 * 32], Bl[128 * 32];
  int row0 = blockIdx.x * 128, col0 = blockIdx.y * 128;
  int t = threadIdx.x, w = t >> 6, l = t & 63;
  int wr = w >> 1, wc = w & 1, g = l >> 4, cl = l & 15;
  f32x4 acc[4][4];
#pragma unroll
  for (int m = 0; m < 4; ++m)
#pragma unroll
    for (int n = 0; n < 4; ++n) acc[m][n] = (f32x4){0.f, 0.f, 0.f, 0.f};
  for (int k0 = 0; k0 < 1024; k0 += 32) {
#pragma unroll
    for (int c = 0; c < 2; ++c) {
      int u = t + 256 * c, row = u >> 2, col = (u & 3) * 8;
      async_cp16(A + (size_t)(row0 + row) * 1024 + k0 + col, &Al[u * 8]);
      async_cp16(B + (size_t)(col0 + row) * 1024 + k0 + col, &Bl[u * 8]);
    }
    __syncthreads();
    bf16x8 af[4], bfr[4];
#pragma unroll
    for (int m = 0; m < 4; ++m) af[m] = *(const bf16x8*)(&Al[(wr * 64 + m * 16 + cl) * 32 + g * 8]);
#pragma unroll
    for (int n = 0; n < 4; ++n) bfr[n] = *(const bf16x8*)(&Bl[(wc * 64 + n * 16 + cl) * 32 + g * 8]);
#pragma unroll
    for (int m = 0; m < 4; ++m)
#pragma unroll
      for (int n = 0; n < 4; ++n)
        acc[m][n] = __builtin_amdgcn_mfma_f32_16x16x32_bf16(af[m], bfr[n], acc[m][n], 0, 0, 0);
    __syncthreads();
  }
  int sec = col0 >> 10;  // block-uniform: 0=q,1=k,2=v
#pragma unroll
  for (int m = 0; m < 4; ++m) {
#pragma unroll
    for (int n = 0; n < 4; ++n) {
#pragma unroll
      for (int r = 0; r < 4; ++r) {
        int row = row0 + wr * 64 + m * 16 + g * 4 + r;
        int col = col0 + wc * 64 + n * 16 + cl;
        int mm = col & 1023, hh = mm >> 6, d = mm & 63;
        int bq = row & 1, iq = row >> 1;
        float val = acc[m][n][r];
        if (sec == 0) {
          qt[(((size_t)bq * 16 + hh) * 2048 + iq) * 64 + d] = f2bf((val + rwb[mm]) * 0.125f);
        } else if (sec == 1) {
          kk[(((size_t)bq * 16 + hh) * 2048 + iq) * 64 + d] = f2bf(val);
        } else {
          // V stored transposed: [b][h][d][j]
          vv[(((size_t)bq * 16 + hh) * 64 + d) * 2048 + iq] = f2bf(val);
        }
      }
    }
  }
}

// ---------------- flash attention with rel-pos band ----------------
// R11-green structure; single change: V^T read direct from global (L2) in PV,
// Vt LDS array removed -> 37.5 KiB LDS -> 4 blocks/CU.

__global__ __launch_bounds__(256, 4) void k_flash(const ushort_t* __restrict__ QT,
                                                  const ushort_t* __restrict__ KK,
                                                  const ushort_t* __restrict__ VT,
                                                  const ushort_t* __restrict__ RE,
                                                  const float* __restrict__ RB2,
                                                  ushort_t* __restrict__ AV) {
  int bh = blockIdx.x, b = bh >> 4, h = bh & 15;
  int i0 = (gridDim.y - 1 - blockIdx.y) * 64;  // longest blocks first
  int t = threadIdx.x, w = t >> 6, l = t & 63, g = l >> 4, cl = l & 15;

  __shared__ ushort_t Klds[64 * 72];   //  9216 B
  __shared__ ushort_t Rl[128 * 72];    // 18432 B  circular by (global_r & 127)
  __shared__ float rb2s[128];          //   512 B  circular
  __shared__ ushort_t Pls[4][16 * 76]; //  9728 B  P bf16 (wave-private, padded stride)
  __shared__ float alphal[4][16];
  __shared__ float lsuml[4][16];
  // total ~37.5 KiB -> 4 blocks/CU

  const ushort_t* qb = QT + ((size_t)(b * 16 + h)) * 2048 * 64;
  const ushort_t* kb = KK + ((size_t)(b * 16 + h)) * 2048 * 64;
  const ushort_t* vt = VT + ((size_t)(b * 16 + h)) * 64 * 2048;
  const ushort_t* rbase = RE + (size_t)h * 2048 * 64;
  const float* r2 = RB2 + h * 2048;

  int qrow = i0 + w * 16 + cl;
  bf16x8 qa0 = *(const bf16x8*)(qb + (size_t)qrow * 64 + g * 8);
  bf16x8 qa1 = *(const bf16x8*)(qb + (size_t)qrow * 64 + 32 + g * 8);

  // per-lane V^T row base for PV global reads: row (dt*16+cl), col j0+g*8(+32)
  const ushort_t* vrow = vt + (size_t)cl * 2048 + g * 8;

  float m_run[4], l_run[4];
  f32x4 Ot[4];
#pragma unroll
  for (int r = 0; r < 4; ++r) { m_run[r] = -1e30f; l_run[r] = 0.f; }
#pragma unroll
  for (int dt = 0; dt < 4; ++dt) Ot[dt] = (f32x4){0.f, 0.f, 0.f, 0.f};

  int nt = gridDim.y - blockIdx.y;  // = i0/64 + 1
  int rb0f = 1984 - i0;
  int urow = t >> 3, ucol = (t & 7) * 8;

  // preload bottom 64 band rows of tile 0 (rows rb0f..rb0f+63, always < 2048)
  *(u32x4*)(&Rl[((rb0f + urow) & 127) * 72 + ucol]) =
      *(const u32x4*)(rbase + (size_t)(rb0f + urow) * 64 + ucol);
  *(u32x4*)(&Rl[((rb0f + urow + 32) & 127) * 72 + ucol]) =
      *(const u32x4*)(rbase + (size_t)(rb0f + urow + 32) * 64 + ucol);
  if (t < 64) rb2s[(rb0f + t) & 127] = r2[rb0f + t];

  // pipeline registers (K + R band; V no longer staged)
  u32x4 kreg0, kreg1, rreg0, rreg1;
  float rb2reg;

  // issue loads for tile 0
  {
    kreg0 = *(const u32x4*)(kb + (size_t)urow * 64 + ucol);
    kreg1 = *(const u32x4*)(kb + (size_t)(urow + 32) * 64 + ucol);
    int gs = rb0f + 64;
    int rr0 = gs + urow, rr1 = gs + urow + 32;
    rreg0 = (rr0 < 2048) ? *(const u32x4*)(rbase + (size_t)rr0 * 64 + ucol) : (u32x4){0u, 0u, 0u, 0u};
    rreg1 = (rr1 < 2048) ? *(const u32x4*)(rbase + (size_t)rr1 * 64 + ucol) : (u32x4){0u, 0u, 0u, 0u};
    int rrb = gs + t;
    rb2reg = (t < 64 && rrb < 2048) ? r2[rrb] : 0.f;
  }

  for (int tt = 0; tt < nt; ++tt) {
    int j0 = tt * 64;
    int rb0 = rb0f + j0;
    __syncthreads();  // (A) previous tile's compute done; LDS free
    // write staged regs -> LDS
    {
      *(u32x4*)(&Klds[urow * 72 + ucol]) = kreg0;
      *(u32x4*)(&Klds[(urow + 32) * 72 + ucol]) = kreg1;
      int gs = rb0 + 64;
      *(u32x4*)(&Rl[((gs + urow) & 127) * 72 + ucol]) = rreg0;
      *(u32x4*)(&Rl[((gs + urow + 32) & 127) * 72 + ucol]) = rreg1;
      if (t < 64) rb2s[(gs + t) & 127] = rb2reg;
    }
    __syncthreads();  // (B) staging visible
    // issue V fragment loads for CURRENT tile (L2-resident; latency hidden
    // under Bw+AC+softmax before PV consumes them)
    bf16x8 vfr[4][2];
#pragma unroll
    for (int dt = 0; dt < 4; ++dt) {
      const ushort_t* vp = vrow + (size_t)dt * 16 * 2048 + j0;
      vfr[dt][0] = *(const bf16x8*)(vp);
      vfr[dt][1] = *(const bf16x8*)(vp + 32);
    }
    // issue next tile's K/R loads (hide latency under compute)
    if (tt + 1 < nt) {
      int j0n = j0 + 64;
      kreg0 = *(const u32x4*)(kb + (size_t)(j0n + urow) * 64 + ucol);
      kreg1 = *(const u32x4*)(kb + (size_t)(j0n + urow + 32) * 64 + ucol);
      int gs = rb0f + j0n + 64;
      int rr0 = gs + urow, rr1 = gs + urow + 32;
      rreg0 = (rr0 < 2048) ? *(const u32x4*)(rbase + (size_t)rr0 * 64 + ucol) : (u32x4){0u, 0u, 0u, 0u};
      rreg1 = (rr1 < 2048) ? *(const u32x4*)(rbase + (size_t)rr1 * 64 + ucol) : (u32x4){0u, 0u, 0u, 0u};
      int rrb = gs + t;
      rb2reg = (t < 64 && rrb < 2048) ? r2[rrb] : 0.f;
    }

    // ---- Bw: q~ strip (16x64) @ R_band^T -> 16x80, kept in REGISTERS ----
    int bw0 = 48 - 16 * w;
    int rB = rb0 + bw0;
    f32x4 bwf[5];
    __builtin_amdgcn_s_setprio(1);
#pragma unroll
    for (int ct = 0; ct < 5; ++ct) {
      int prow = (rB + ct * 16) & 127;  // multiple of 16
      f32x4 a = (f32x4){0.f, 0.f, 0.f, 0.f};
      bf16x8 rr0 = *(const bf16x8*)(&Rl[(prow + cl) * 72 + g * 8]);
      a = __builtin_amdgcn_mfma_f32_16x16x32_bf16(qa0, rr0, a, 0, 0, 0);
      bf16x8 rr1 = *(const bf16x8*)(&Rl[(prow + cl) * 72 + 32 + g * 8]);
      a = __builtin_amdgcn_mfma_f32_16x16x32_bf16(qa1, rr1, a, 0, 0, 0);
      float rv = rb2s[(prow + cl) & 127];  // same circular slot as the R row
      a[0] += rv; a[1] += rv; a[2] += rv; a[3] += rv;
      bwf[ct] = a;
    }

    // ---- AC = q~ @ K^T ----
    f32x4 S[4];
#pragma unroll
    for (int ct = 0; ct < 4; ++ct) {
      f32x4 a = (f32x4){0.f, 0.f, 0.f, 0.f};
      bf16x8 kf0 = *(const bf16x8*)(&Klds[(ct * 16 + cl) * 72 + g * 8]);
      a = __builtin_amdgcn_mfma_f32_16x16x32_bf16(qa0, kf0, a, 0, 0, 0);
      bf16x8 kf1 = *(const bf16x8*)(&Klds[(ct * 16 + cl) * 72 + 32 + g * 8]);
      a = __builtin_amdgcn_mfma_f32_16x16x32_bf16(qa1, kf1, a, 0, 0, 0);
      S[ct] = a;
    }
    __builtin_amdgcn_s_setprio(0);

    // ---- scores + mask (diag tile only) + online softmax (DPP reductions) ----
    bool diag = (tt == nt - 1);
    int climit = i0 - j0 + 15 + 16 * w;
#pragma unroll
    for (int r = 0; r < 4; ++r) {
      int rl = g * 4 + r;
      int dlt = cl - rl + 15;               // in [0,30]
      int src = (l & 48) | (dlt & 15);
      float b0 = __shfl(bwf[0][r], src);
      float b1 = __shfl(bwf[1][r], src);
      float b2 = __shfl(bwf[2][r], src);
      float b3 = __shfl(bwf[3][r], src);
      float b4 = __shfl(bwf[4][r], src);
      if (dlt >= 16) { b0 = b1; b1 = b2; b2 = b3; b3 = b4; }
      float sv[4];
      if (diag) {
        sv[0] = (dlt      <= climit) ? S[0][r] + b0 : -1e30f;
        sv[1] = (dlt + 16 <= climit) ? S[1][r] + b1 : -1e30f;
        sv[2] = (dlt + 32 <= climit) ? S[2][r] + b2 : -1e30f;
        sv[3] = (dlt + 48 <= climit) ? S[3][r] + b3 : -1e30f;
      } else {
        sv[0] = S[0][r] + b0;
        sv[1] = S[1][r] + b1;
        sv[2] = S[2][r] + b2;
        sv[3] = S[3][r] + b3;
      }
      float rmax = fmaxf(fmaxf(sv[0], sv[1]), fmaxf(sv[2], sv[3]));
      rmax = row16_max(rmax);                 // DPP, VALU pipe
      float mn = fmaxf(m_run[r], rmax);
      float al = __expf(m_run[r] - mn);
      m_run[r] = mn;
      float rsum = 0.f;
#pragma unroll
      for (int ct = 0; ct < 4; ++ct) {
        float pv = __expf(sv[ct] - mn);
        sv[ct] = pv;
        rsum += pv;
      }
      rsum = row16_sum(rsum);                 // DPP, VALU pipe
      l_run[r] = l_run[r] * al + rsum;
      if (cl == 0) alphal[w][rl] = al;
#pragma unroll
      for (int ct = 0; ct < 4; ++ct)
        Pls[w][rl * 76 + ct * 16 + cl] = f2bf(sv[ct]);
    }
    // no barrier: Pls/alphal wave-private; same-wave DS ops program-ordered

    // ---- O^T += V^T @ P^T (V fragments from global/L2) ----
    float aq = alphal[w][cl];
    bf16x8 pb0 = *(const bf16x8*)(&Pls[w][cl * 76 + g * 8]);
    bf16x8 pb1 = *(const bf16x8*)(&Pls[w][cl * 76 + 32 + g * 8]);
    __builtin_amdgcn_s_setprio(1);
#pragma unroll
    for (int dt = 0; dt < 4; ++dt) {
      f32x4 o = Ot[dt];
      o[0] *= aq; o[1] *= aq; o[2] *= aq; o[3] *= aq;
      o = __builtin_amdgcn_mfma_f32_16x16x32_bf16(vfr[dt][0], pb0, o, 0, 0, 0);
      o = __builtin_amdgcn_mfma_f32_16x16x32_bf16(vfr[dt][1], pb1, o, 0, 0, 0);
      Ot[dt] = o;
    }
    __builtin_amdgcn_s_setprio(0);
  }

  if (cl == 0) {
#pragma unroll
    for (int r = 0; r < 4; ++r) lsuml[w][g * 4 + r] = l_run[r];
  }
  float inv = 1.f / lsuml[w][cl];
  int orow = (i0 + w * 16 + cl) * 2 + b;
#pragma unroll
  for (int dt = 0; dt < 4; ++dt) {
    us4 o4;
    o4[0] = f2bf(Ot[dt][0] * inv);
    o4[1] = f2bf(Ot[dt][1] * inv);
    o4[2] = f2bf(Ot[dt][2] * inv);
    o4[3] = f2bf(Ot[dt][3] * inv);
    *(us4*)(&AV[(size_t)orow * 1024 + h * 64 + dt * 16 + g * 4]) = o4;
  }
}

// ---------------- GEMM 2: attn_vec @ W_o + w -> Y ----------------

__global__ __launch_bounds__(256) void k_gemm_o(const ushort_t* __restrict__ A,
                                                const ushort_t* __restrict__ B,
                                                const float* __restrict__ wsrc,
                                                float* __restrict__ Y) {
  __shared__ ushort_t Al[128 * 32], Bl[128 * 32];
  int row0 = blockIdx.x * 128, col0 = blockIdx.y * 128;
  int t = threadIdx.x, w = t >> 6, l = t & 63;
  int wr = w >> 1, wc = w & 1, g = l >> 4, cl = l & 15;
  f32x4 acc[4][4];
#pragma unroll
  for (int m = 0; m < 4; ++m)
#pragma unroll
    for (int n = 0; n < 4; ++n) acc[m][n] = (f32x4){0.f, 0.f, 0.f, 0.f};
  for (int k0 = 0; k0 < 1024; k0 += 32) {
#pragma unroll
    for (int c = 0; c < 2; ++c) {
      int u = t + 256 * c, row = u >> 2, col = (u & 3) * 8;
      async_cp16(A + (size_t)(row0 + row) * 1024 + k0 + col, &Al[u * 8]);
      async_cp16(B + (size_t)(col0 + row) * 1024 + k0 + col, &Bl[u * 8]);
    }
    __syncthreads();
    bf16x8 af[4], bfr[4];
#pragma unroll
    for (int m = 0; m < 4; ++m) af[m] = *(const bf16x8*)(&Al[(wr * 64 + m * 16 + cl) * 32 + g * 8]);
#pragma unroll
    for (int n = 0; n < 4; ++n) bfr[n] = *(const bf16x8*)(&Bl[(wc * 64 + n * 16 + cl) * 32 + g * 8]);
#pragma unroll
    for (int m = 0; m < 4; ++m)
#pragma unroll
      for (int n = 0; n < 4; ++n)
        acc[m][n] = __builtin_amdgcn_mfma_f32_16x16x32_bf16(af[m], bfr[n], acc[m][n], 0, 0, 0);
    __syncthreads();
  }
#pragma unroll
  for (int m = 0; m < 4; ++m) {
#pragma unroll
    for (int n = 0; n < 4; ++n) {
#pragma unroll
      for (int r = 0; r < 4; ++r) {
        int row = row0 + wr * 64 + m * 16 + g * 4 + r;
        int col = col0 + wc * 64 + n * 16 + cl;
        size_t idx = (size_t)row * 1024 + col;
        Y[idx] = acc[m][n][r] + wsrc[idx];
      }
    }
  }
}

// ---------------- LayerNorm ----------------

__global__ __launch_bounds__(256) void k_ln(const float* __restrict__ Y,
                                            const float* __restrict__ gg,
                                            const float* __restrict__ bb,
                                            float* __restrict__ out) {
  int row = blockIdx.x, t = threadIdx.x;
  float4 v = *(const float4*)(Y + (size_t)row * 1024 + t * 4);
  float s = v.x + v.y + v.z + v.w;
  float q = v.x * v.x + v.y * v.y + v.z * v.z + v.w * v.w;
#pragma unroll
  for (int m = 32; m >= 1; m >>= 1) {
    s += __shfl_xor(s, m);
    q += __shfl_xor(q, m);
  }
  __shared__ float ssh[4], qsh[4];
  int w = t >> 6, l = t & 63;
  if (l == 0) { ssh[w] = s; qsh[w] = q; }
  __syncthreads();
  s = ssh[0] + ssh[1] + ssh[2] + ssh[3];
  q = qsh[0] + qsh[1] + qsh[2] + qsh[3];
  float mu = s * (1.f / 1024.f);
  float var = q * (1.f / 1024.f) - mu * mu;
  float rstd = rsqrtf(var + 1e-5f);
  float4 gv = *(const float4*)(gg + t * 4);
  float4 bv = *(const float4*)(bb + t * 4);
  float4 o;
  o.x = (v.x - mu) * rstd * gv.x + bv.x;
  o.y = (v.y - mu) * rstd * gv.y + bv.y;
  o.z = (v.z - mu) * rstd * gv.z + bv.z;
  o.w = (v.w - mu) * rstd * gv.w + bv.w;
  *(float4*)(out + (size_t)row * 1024 + t * 4) = o;
}

// ---------------- launch ----------------

extern "C" void kernel_launch(void* const* d_in, const int* in_sizes, int n_in,
                              void* d_out, int out_size, void* d_ws, size_t ws_size,
                              hipStream_t stream) {
  const float* w      = (const float*)d_in[0];
  const float* r_emb  = (const float*)d_in[1];
  const float* r_w_b  = (const float*)d_in[2];
  const float* r_bias = (const float*)d_in[3];
  // d_in[4] attn_mask: implemented analytically (causal)
  const float* W_qkv  = (const float*)d_in[5];
  const float* W_o    = (const float*)d_in[6];
  const float* ln_g   = (const float*)d_in[7];
  const float* ln_b   = (const float*)d_in[8];
  float* out = (float*)d_out;
  char* ws = (char*)d_ws;

  ushort_t* X16  = (ushort_t*)(ws + 0);          //  8,388,608 B  x bf16
  ushort_t* WQ16 = (ushort_t*)(ws + 8388608);    //  6,291,456 B  Wqkv^T bf16 [3072][1024]
  ushort_t* WO16 = (ushort_t*)(ws + 14680064);   //  2,097,152 B  Wo^T bf16 [1024][1024]
  ushort_t* RE16 = (ushort_t*)(ws + 16777216);   //  4,194,304 B  r_emb bf16 [h][r][d]
  float*    RB2  = (float*)(ws + 20971520);      //    131,072 B  rbias2[h][r] (pre-scaled)
  ushort_t* QT16 = (ushort_t*)(ws + 21102592);   //  8,388,608 B  q~ bf16 [b][h][i][d] (pre-scaled)
  ushort_t* K16  = (ushort_t*)(ws + 29491200);   //  8,388,608 B  [b][h][i][d]
  ushort_t* VT16 = (ushort_t*)(ws + 37879808);   //  8,388,608 B  V^T [b][h][d][j]
  ushort_t* AV16 = (ushort_t*)(ws + 46268416);   //  8,388,608 B  attn_vec bf16 [4096][1024]
  float*    Y32  = (float*)(ws + 54657024);      // 16,777,216 B  y fp32

  k_conv_x<<<4096, 256, 0, stream>>>(w, X16);
  k_transpose_bf16<<<dim3(96, 32), dim3(32, 8), 0, stream>>>(W_qkv, WQ16, 1024, 3072);
  k_transpose_bf16<<<dim3(32, 32), dim3(32, 8), 0, stream>>>(W_o, WO16, 1024, 1024);
  k_conv_remb<<<1024, 256, 0, stream>>>(r_emb, RE16);
  k_rbias2<<<128, 256, 0, stream>>>(RE16, r_w_b, r_bias, RB2);
  k_gemm_qkv<<<dim3(32, 24), 256, 0, stream>>>(X16, WQ16, r_w_b, QT16, K16, VT16);
  k_flash<<<dim3(32, 32), 256, 0, stream>>>(QT16, K16, VT16, RE16, RB2, AV16);
  k_gemm_o<<<dim3(32, 8), 256, 0, stream>>>(AV16, WO16, w, Y32);
  k_ln<<<4096, 256, 0, stream>>>(Y32, ln_g, ln_b, out);
}

// Round 13
// 179.671 us; speedup vs baseline: 1.7637x; 1.7637x over previous
//
#include <hip/hip_runtime.h>

typedef unsigned short ushort_t;
typedef unsigned short us4 __attribute__((ext_vector_type(4)));
typedef unsigned short us8 __attribute__((ext_vector_type(8)));
typedef unsigned int   u32x4 __attribute__((ext_vector_type(4)));
typedef float          f32x4 __attribute__((ext_vector_type(4)));
typedef __bf16         bf16x8 __attribute__((ext_vector_type(8)));

__device__ __forceinline__ unsigned short f2bf(float f) {
  unsigned u = __builtin_bit_cast(unsigned, f);
  u += 0x7fffu + ((u >> 16) & 1u);
  return (unsigned short)(u >> 16);
}
__device__ __forceinline__ float bf2f(unsigned short h) {
  unsigned u = ((unsigned)h) << 16;
  return __builtin_bit_cast(float, u);
}

// async 16B global -> LDS (wave-uniform LDS base + lane*16; lane-linear here)
__device__ __forceinline__ void async_cp16(const ushort_t* g, ushort_t* l) {
  __builtin_amdgcn_global_load_lds(
      (const __attribute__((address_space(1))) unsigned int*)g,
      (__attribute__((address_space(3))) unsigned int*)l, 16, 0, 0);
}

// DPP row-rotate (16-lane row) — VALU-pipe cross-lane, replaces ds_bpermute
template <int CTRL>
__device__ __forceinline__ float dpp_rotf(float x) {
  return __builtin_bit_cast(float,
      __builtin_amdgcn_update_dpp(0, __builtin_bit_cast(int, x), CTRL, 0xF, 0xF, true));
}
// 16-lane reduction via row_ror 1,2,4,8 (covers all 16 lanes, any commutative op)
__device__ __forceinline__ float row16_max(float x) {
  x = fmaxf(x, dpp_rotf<0x121>(x));
  x = fmaxf(x, dpp_rotf<0x122>(x));
  x = fmaxf(x, dpp_rotf<0x124>(x));
  x = fmaxf(x, dpp_rotf<0x128>(x));
  return x;
}
__device__ __forceinline__ float row16_sum(float x) {
  x += dpp_rotf<0x121>(x);
  x += dpp_rotf<0x122>(x);
  x += dpp_rotf<0x124>(x);
  x += dpp_rotf<0x128>(x);
  return x;
}

// ---------------- prep kernels ----------------

__global__ __launch_bounds__(256) void k_conv_x(const float* __restrict__ in,
                                                ushort_t* __restrict__ out) {
  int i = (blockIdx.x * 256 + threadIdx.x) * 4;
  float4 v = *(const float4*)(in + i);
  us4 o;
  o[0] = f2bf(v.x); o[1] = f2bf(v.y); o[2] = f2bf(v.z); o[3] = f2bf(v.w);
  *(us4*)(out + i) = o;
}

// in[R][C] f32 -> out[C][R] bf16
__global__ __launch_bounds__(256) void k_transpose_bf16(const float* __restrict__ in,
                                                        ushort_t* __restrict__ out,
                                                        int R, int C) {
  __shared__ float tile[32][33];
  int c0 = blockIdx.x * 32, r0 = blockIdx.y * 32;
  int tx = threadIdx.x, ty = threadIdx.y;
#pragma unroll
  for (int k = 0; k < 32; k += 8)
    tile[ty + k][tx] = in[(size_t)(r0 + ty + k) * C + c0 + tx];
  __syncthreads();
#pragma unroll
  for (int k = 0; k < 32; k += 8)
    out[(size_t)(c0 + ty + k) * R + r0 + tx] = f2bf(tile[tx][ty + k]);
}

// r_emb (r, h, d) f32 -> RE16 [h][r][d] bf16
__global__ __launch_bounds__(256) void k_conv_remb(const float* __restrict__ re,
                                                   ushort_t* __restrict__ out) {
  int tid = blockIdx.x * 256 + threadIdx.x;
  int o = tid * 8;
  int d = o & 63, r = (o >> 6) & 2047, h = o >> 17;
  const float* src = re + ((size_t)r * 16 + h) * 64 + d;
  float4 a = *(const float4*)(src);
  float4 b = *(const float4*)(src + 4);
  us8 u;
  u[0] = f2bf(a.x); u[1] = f2bf(a.y); u[2] = f2bf(a.z); u[3] = f2bf(a.w);
  u[4] = f2bf(b.x); u[5] = f2bf(b.y); u[6] = f2bf(b.z); u[7] = f2bf(b.w);
  *(us8*)(out + o) = u;
}

// rbias2[h][r] = (r_bias[r][h] - dot(r_w_bias[h], r_emb_bf16[h][r])) * SCALE
__global__ __launch_bounds__(256) void k_rbias2(const ushort_t* __restrict__ RE,
                                                const float* __restrict__ rwb,
                                                const float* __restrict__ rbias,
                                                float* __restrict__ out) {
  int tid = blockIdx.x * 256 + threadIdx.x;  // 32768 total
  int h = tid >> 11, r = tid & 2047;
  const ushort_t* re = RE + ((size_t)h * 2048 + r) * 64;
  const float* wv = rwb + h * 64;
  float acc = 0.f;
#pragma unroll
  for (int d0 = 0; d0 < 64; d0 += 8) {
    us8 v = *(const us8*)(re + d0);
#pragma unroll
    for (int e = 0; e < 8; ++e) acc += bf2f(v[e]) * wv[d0 + e];
  }
  out[h * 2048 + r] = (rbias[r * 16 + h] - acc) * 0.125f;
}

// ---------------- GEMM 1: X(4096x1024) @ Wqkv -> scatter q~,k,v^T ----------------

__global__ __launch_bounds__(256) void k_gemm_qkv(const ushort_t* __restrict__ A,
                                                  const ushort_t* __restrict__ B,
                                                  const float* __restrict__ rwb,
                                                  ushort_t* __restrict__ qt,
                                                  ushort_t* __restrict__ kk,
                                                  ushort_t* __restrict__ vv) {
  __shared__ ushort_t Al[128 * 32], Bl[128 * 32];
  int row0 = blockIdx.x * 128, col0 = blockIdx.y * 128;
  int t = threadIdx.x, w = t >> 6, l = t & 63;
  int wr = w >> 1, wc = w & 1, g = l >> 4, cl = l & 15;
  f32x4 acc[4][4];
#pragma unroll
  for (int m = 0; m < 4; ++m)
#pragma unroll
    for (int n = 0; n < 4; ++n) acc[m][n] = (f32x4){0.f, 0.f, 0.f, 0.f};
  for (int k0 = 0; k0 < 1024; k0 += 32) {
#pragma unroll
    for (int c = 0; c < 2; ++c) {
      int u = t + 256 * c, row = u >> 2, col = (u & 3) * 8;
      async_cp16(A + (size_t)(row0 + row) * 1024 + k0 + col, &Al[u * 8]);
      async_cp16(B + (size_t)(col0 + row) * 1024 + k0 + col, &Bl[u * 8]);
    }
    __syncthreads();
    bf16x8 af[4], bfr[4];
#pragma unroll
    for (int m = 0; m < 4; ++m) af[m] = *(const bf16x8*)(&Al[(wr * 64 + m * 16 + cl) * 32 + g * 8]);
#pragma unroll
    for (int n = 0; n < 4; ++n) bfr[n] = *(const bf16x8*)(&Bl[(wc * 64 + n * 16 + cl) * 32 + g * 8]);
#pragma unroll
    for (int m = 0; m < 4; ++m)
#pragma unroll
      for (int n = 0; n < 4; ++n)
        acc[m][n] = __builtin_amdgcn_mfma_f32_16x16x32_bf16(af[m], bfr[n], acc[m][n], 0, 0, 0);
    __syncthreads();
  }
  int sec = col0 >> 10;  // block-uniform: 0=q,1=k,2=v
#pragma unroll
  for (int m = 0; m < 4; ++m) {
#pragma unroll
    for (int n = 0; n < 4; ++n) {
#pragma unroll
      for (int r = 0; r < 4; ++r) {
        int row = row0 + wr * 64 + m * 16 + g * 4 + r;
        int col = col0 + wc * 64 + n * 16 + cl;
        int mm = col & 1023, hh = mm >> 6, d = mm & 63;
        int bq = row & 1, iq = row >> 1;
        float val = acc[m][n][r];
        if (sec == 0) {
          qt[(((size_t)bq * 16 + hh) * 2048 + iq) * 64 + d] = f2bf((val + rwb[mm]) * 0.125f);
        } else if (sec == 1) {
          kk[(((size_t)bq * 16 + hh) * 2048 + iq) * 64 + d] = f2bf(val);
        } else {
          // V stored transposed: [b][h][d][j]
          vv[(((size_t)bq * 16 + hh) * 64 + d) * 2048 + iq] = f2bf(val);
        }
      }
    }
  }
}

// ---------------- flash attention with rel-pos band ----------------
// R11-green structure + V^T from global (L2) in PV; launch_bounds (256,3)
// (R12's (256,4) squeezed VGPR to 64 -> scratch spill, WRITE_SIZE 188MB).

__global__ __launch_bounds__(256, 3) void k_flash(const ushort_t* __restrict__ QT,
                                                  const ushort_t* __restrict__ KK,
                                                  const ushort_t* __restrict__ VT,
                                                  const ushort_t* __restrict__ RE,
                                                  const float* __restrict__ RB2,
                                                  ushort_t* __restrict__ AV) {
  int bh = blockIdx.x, b = bh >> 4, h = bh & 15;
  int i0 = (gridDim.y - 1 - blockIdx.y) * 64;  // longest blocks first
  int t = threadIdx.x, w = t >> 6, l = t & 63, g = l >> 4, cl = l & 15;

  __shared__ ushort_t Klds[64 * 72];   //  9216 B
  __shared__ ushort_t Rl[128 * 72];    // 18432 B  circular by (global_r & 127)
  __shared__ float rb2s[128];          //   512 B  circular
  __shared__ ushort_t Pls[4][16 * 76]; //  9728 B  P bf16 (wave-private, padded stride)
  __shared__ float alphal[4][16];
  __shared__ float lsuml[4][16];
  // total ~37.5 KiB

  const ushort_t* qb = QT + ((size_t)(b * 16 + h)) * 2048 * 64;
  const ushort_t* kb = KK + ((size_t)(b * 16 + h)) * 2048 * 64;
  const ushort_t* vt = VT + ((size_t)(b * 16 + h)) * 64 * 2048;
  const ushort_t* rbase = RE + (size_t)h * 2048 * 64;
  const float* r2 = RB2 + h * 2048;

  int qrow = i0 + w * 16 + cl;
  bf16x8 qa0 = *(const bf16x8*)(qb + (size_t)qrow * 64 + g * 8);
  bf16x8 qa1 = *(const bf16x8*)(qb + (size_t)qrow * 64 + 32 + g * 8);

  // per-lane V^T row base for PV global reads: row (dt*16+cl), col j0+g*8(+32)
  const ushort_t* vrow = vt + (size_t)cl * 2048 + g * 8;

  float m_run[4], l_run[4];
  f32x4 Ot[4];
#pragma unroll
  for (int r = 0; r < 4; ++r) { m_run[r] = -1e30f; l_run[r] = 0.f; }
#pragma unroll
  for (int dt = 0; dt < 4; ++dt) Ot[dt] = (f32x4){0.f, 0.f, 0.f, 0.f};

  int nt = gridDim.y - blockIdx.y;  // = i0/64 + 1
  int rb0f = 1984 - i0;
  int urow = t >> 3, ucol = (t & 7) * 8;

  // preload bottom 64 band rows of tile 0 (rows rb0f..rb0f+63, always < 2048)
  *(u32x4*)(&Rl[((rb0f + urow) & 127) * 72 + ucol]) =
      *(const u32x4*)(rbase + (size_t)(rb0f + urow) * 64 + ucol);
  *(u32x4*)(&Rl[((rb0f + urow + 32) & 127) * 72 + ucol]) =
      *(const u32x4*)(rbase + (size_t)(rb0f + urow + 32) * 64 + ucol);
  if (t < 64) rb2s[(rb0f + t) & 127] = r2[rb0f + t];

  // pipeline registers (K + R band; V no longer staged)
  u32x4 kreg0, kreg1, rreg0, rreg1;
  float rb2reg;

  // issue loads for tile 0
  {
    kreg0 = *(const u32x4*)(kb + (size_t)urow * 64 + ucol);
    kreg1 = *(const u32x4*)(kb + (size_t)(urow + 32) * 64 + ucol);
    int gs = rb0f + 64;
    int rr0 = gs + urow, rr1 = gs + urow + 32;
    rreg0 = (rr0 < 2048) ? *(const u32x4*)(rbase + (size_t)rr0 * 64 + ucol) : (u32x4){0u, 0u, 0u, 0u};
    rreg1 = (rr1 < 2048) ? *(const u32x4*)(rbase + (size_t)rr1 * 64 + ucol) : (u32x4){0u, 0u, 0u, 0u};
    int rrb = gs + t;
    rb2reg = (t < 64 && rrb < 2048) ? r2[rrb] : 0.f;
  }

  for (int tt = 0; tt < nt; ++tt) {
    int j0 = tt * 64;
    int rb0 = rb0f + j0;
    __syncthreads();  // (A) previous tile's compute done; LDS free
    // write staged regs -> LDS
    {
      *(u32x4*)(&Klds[urow * 72 + ucol]) = kreg0;
      *(u32x4*)(&Klds[(urow + 32) * 72 + ucol]) = kreg1;
      int gs = rb0 + 64;
      *(u32x4*)(&Rl[((gs + urow) & 127) * 72 + ucol]) = rreg0;
      *(u32x4*)(&Rl[((gs + urow + 32) & 127) * 72 + ucol]) = rreg1;
      if (t < 64) rb2s[(gs + t) & 127] = rb2reg;
    }
    __syncthreads();  // (B) staging visible
    // issue V fragment loads for CURRENT tile (L2-resident; latency hidden
    // under Bw+AC+softmax before PV consumes them)
    bf16x8 vfr[4][2];
#pragma unroll
    for (int dt = 0; dt < 4; ++dt) {
      const ushort_t* vp = vrow + (size_t)dt * 16 * 2048 + j0;
      vfr[dt][0] = *(const bf16x8*)(vp);
      vfr[dt][1] = *(const bf16x8*)(vp + 32);
    }
    // issue next tile's K/R loads (hide latency under compute)
    if (tt + 1 < nt) {
      int j0n = j0 + 64;
      kreg0 = *(const u32x4*)(kb + (size_t)(j0n + urow) * 64 + ucol);
      kreg1 = *(const u32x4*)(kb + (size_t)(j0n + urow + 32) * 64 + ucol);
      int gs = rb0f + j0n + 64;
      int rr0 = gs + urow, rr1 = gs + urow + 32;
      rreg0 = (rr0 < 2048) ? *(const u32x4*)(rbase + (size_t)rr0 * 64 + ucol) : (u32x4){0u, 0u, 0u, 0u};
      rreg1 = (rr1 < 2048) ? *(const u32x4*)(rbase + (size_t)rr1 * 64 + ucol) : (u32x4){0u, 0u, 0u, 0u};
      int rrb = gs + t;
      rb2reg = (t < 64 && rrb < 2048) ? r2[rrb] : 0.f;
    }

    // ---- Bw: q~ strip (16x64) @ R_band^T -> 16x80, kept in REGISTERS ----
    int bw0 = 48 - 16 * w;
    int rB = rb0 + bw0;
    f32x4 bwf[5];
    __builtin_amdgcn_s_setprio(1);
#pragma unroll
    for (int ct = 0; ct < 5; ++ct) {
      int prow = (rB + ct * 16) & 127;  // multiple of 16
      f32x4 a = (f32x4){0.f, 0.f, 0.f, 0.f};
      bf16x8 rr0 = *(const bf16x8*)(&Rl[(prow + cl) * 72 + g * 8]);
      a = __builtin_amdgcn_mfma_f32_16x16x32_bf16(qa0, rr0, a, 0, 0, 0);
      bf16x8 rr1 = *(const bf16x8*)(&Rl[(prow + cl) * 72 + 32 + g * 8]);
      a = __builtin_amdgcn_mfma_f32_16x16x32_bf16(qa1, rr1, a, 0, 0, 0);
      float rv = rb2s[(prow + cl) & 127];  // same circular slot as the R row
      a[0] += rv; a[1] += rv; a[2] += rv; a[3] += rv;
      bwf[ct] = a;
    }

    // ---- AC = q~ @ K^T ----
    f32x4 S[4];
#pragma unroll
    for (int ct = 0; ct < 4; ++ct) {
      f32x4 a = (f32x4){0.f, 0.f, 0.f, 0.f};
      bf16x8 kf0 = *(const bf16x8*)(&Klds[(ct * 16 + cl) * 72 + g * 8]);
      a = __builtin_amdgcn_mfma_f32_16x16x32_bf16(qa0, kf0, a, 0, 0, 0);
      bf16x8 kf1 = *(const bf16x8*)(&Klds[(ct * 16 + cl) * 72 + 32 + g * 8]);
      a = __builtin_amdgcn_mfma_f32_16x16x32_bf16(qa1, kf1, a, 0, 0, 0);
      S[ct] = a;
    }
    __builtin_amdgcn_s_setprio(0);

    // ---- scores + mask (diag tile only) + online softmax (DPP reductions) ----
    bool diag = (tt == nt - 1);
    int climit = i0 - j0 + 15 + 16 * w;
#pragma unroll
    for (int r = 0; r < 4; ++r) {
      int rl = g * 4 + r;
      int dlt = cl - rl + 15;               // in [0,30]
      int src = (l & 48) | (dlt & 15);
      float b0 = __shfl(bwf[0][r], src);
      float b1 = __shfl(bwf[1][r], src);
      float b2 = __shfl(bwf[2][r], src);
      float b3 = __shfl(bwf[3][r], src);
      float b4 = __shfl(bwf[4][r], src);
      if (dlt >= 16) { b0 = b1; b1 = b2; b2 = b3; b3 = b4; }
      float sv[4];
      if (diag) {
        sv[0] = (dlt      <= climit) ? S[0][r] + b0 : -1e30f;
        sv[1] = (dlt + 16 <= climit) ? S[1][r] + b1 : -1e30f;
        sv[2] = (dlt + 32 <= climit) ? S[2][r] + b2 : -1e30f;
        sv[3] = (dlt + 48 <= climit) ? S[3][r] + b3 : -1e30f;
      } else {
        sv[0] = S[0][r] + b0;
        sv[1] = S[1][r] + b1;
        sv[2] = S[2][r] + b2;
        sv[3] = S[3][r] + b3;
      }
      float rmax = fmaxf(fmaxf(sv[0], sv[1]), fmaxf(sv[2], sv[3]));
      rmax = row16_max(rmax);                 // DPP, VALU pipe
      float mn = fmaxf(m_run[r], rmax);
      float al = __expf(m_run[r] - mn);
      m_run[r] = mn;
      float rsum = 0.f;
#pragma unroll
      for (int ct = 0; ct < 4; ++ct) {
        float pv = __expf(sv[ct] - mn);
        sv[ct] = pv;
        rsum += pv;
      }
      rsum = row16_sum(rsum);                 // DPP, VALU pipe
      l_run[r] = l_run[r] * al + rsum;
      if (cl == 0) alphal[w][rl] = al;
#pragma unroll
      for (int ct = 0; ct < 4; ++ct)
        Pls[w][rl * 76 + ct * 16 + cl] = f2bf(sv[ct]);
    }
    // no barrier: Pls/alphal wave-private; same-wave DS ops program-ordered

    // ---- O^T += V^T @ P^T (V fragments from global/L2) ----
    float aq = alphal[w][cl];
    bf16x8 pb0 = *(const bf16x8*)(&Pls[w][cl * 76 + g * 8]);
    bf16x8 pb1 = *(const bf16x8*)(&Pls[w][cl * 76 + 32 + g * 8]);
    __builtin_amdgcn_s_setprio(1);
#pragma unroll
    for (int dt = 0; dt < 4; ++dt) {
      f32x4 o = Ot[dt];
      o[0] *= aq; o[1] *= aq; o[2] *= aq; o[3] *= aq;
      o = __builtin_amdgcn_mfma_f32_16x16x32_bf16(vfr[dt][0], pb0, o, 0, 0, 0);
      o = __builtin_amdgcn_mfma_f32_16x16x32_bf16(vfr[dt][1], pb1, o, 0, 0, 0);
      Ot[dt] = o;
    }
    __builtin_amdgcn_s_setprio(0);
  }

  if (cl == 0) {
#pragma unroll
    for (int r = 0; r < 4; ++r) lsuml[w][g * 4 + r] = l_run[r];
  }
  float inv = 1.f / lsuml[w][cl];
  int orow = (i0 + w * 16 + cl) * 2 + b;
#pragma unroll
  for (int dt = 0; dt < 4; ++dt) {
    us4 o4;
    o4[0] = f2bf(Ot[dt][0] * inv);
    o4[1] = f2bf(Ot[dt][1] * inv);
    o4[2] = f2bf(Ot[dt][2] * inv);
    o4[3] = f2bf(Ot[dt][3] * inv);
    *(us4*)(&AV[(size_t)orow * 1024 + h * 64 + dt * 16 + g * 4]) = o4;
  }
}

// ---------------- GEMM 2: attn_vec @ W_o + w -> Y ----------------

__global__ __launch_bounds__(256) void k_gemm_o(const ushort_t* __restrict__ A,
                                                const ushort_t* __restrict__ B,
                                                const float* __restrict__ wsrc,
                                                float* __restrict__ Y) {
  __shared__ ushort_t Al[128 * 32], Bl[128 * 32];
  int row0 = blockIdx.x * 128, col0 = blockIdx.y * 128;
  int t = threadIdx.x, w = t >> 6, l = t & 63;
  int wr = w >> 1, wc = w & 1, g = l >> 4, cl = l & 15;
  f32x4 acc[4][4];
#pragma unroll
  for (int m = 0; m < 4; ++m)
#pragma unroll
    for (int n = 0; n < 4; ++n) acc[m][n] = (f32x4){0.f, 0.f, 0.f, 0.f};
  for (int k0 = 0; k0 < 1024; k0 += 32) {
#pragma unroll
    for (int c = 0; c < 2; ++c) {
      int u = t + 256 * c, row = u >> 2, col = (u & 3) * 8;
      async_cp16(A + (size_t)(row0 + row) * 1024 + k0 + col, &Al[u * 8]);
      async_cp16(B + (size_t)(col0 + row) * 1024 + k0 + col, &Bl[u * 8]);
    }
    __syncthreads();
    bf16x8 af[4], bfr[4];
#pragma unroll
    for (int m = 0; m < 4; ++m) af[m] = *(const bf16x8*)(&Al[(wr * 64 + m * 16 + cl) * 32 + g * 8]);
#pragma unroll
    for (int n = 0; n < 4; ++n) bfr[n] = *(const bf16x8*)(&Bl[(wc * 64 + n * 16 + cl) * 32 + g * 8]);
#pragma unroll
    for (int m = 0; m < 4; ++m)
#pragma unroll
      for (int n = 0; n < 4; ++n)
        acc[m][n] = __builtin_amdgcn_mfma_f32_16x16x32_bf16(af[m], bfr[n], acc[m][n], 0, 0, 0);
    __syncthreads();
  }
#pragma unroll
  for (int m = 0; m < 4; ++m) {
#pragma unroll
    for (int n = 0; n < 4; ++n) {
#pragma unroll
      for (int r = 0; r < 4; ++r) {
        int row = row0 + wr * 64 + m * 16 + g * 4 + r;
        int col = col0 + wc * 64 + n * 16 + cl;
        size_t idx = (size_t)row * 1024 + col;
        Y[idx] = acc[m][n][r] + wsrc[idx];
      }
    }
  }
}

// ---------------- LayerNorm ----------------

__global__ __launch_bounds__(256) void k_ln(const float* __restrict__ Y,
                                            const float* __restrict__ gg,
                                            const float* __restrict__ bb,
                                            float* __restrict__ out) {
  int row = blockIdx.x, t = threadIdx.x;
  float4 v = *(const float4*)(Y + (size_t)row * 1024 + t * 4);
  float s = v.x + v.y + v.z + v.w;
  float q = v.x * v.x + v.y * v.y + v.z * v.z + v.w * v.w;
#pragma unroll
  for (int m = 32; m >= 1; m >>= 1) {
    s += __shfl_xor(s, m);
    q += __shfl_xor(q, m);
  }
  __shared__ float ssh[4], qsh[4];
  int w = t >> 6, l = t & 63;
  if (l == 0) { ssh[w] = s; qsh[w] = q; }
  __syncthreads();
  s = ssh[0] + ssh[1] + ssh[2] + ssh[3];
  q = qsh[0] + qsh[1] + qsh[2] + qsh[3];
  float mu = s * (1.f / 1024.f);
  float var = q * (1.f / 1024.f) - mu * mu;
  float rstd = rsqrtf(var + 1e-5f);
  float4 gv = *(const float4*)(gg + t * 4);
  float4 bv = *(const float4*)(bb + t * 4);
  float4 o;
  o.x = (v.x - mu) * rstd * gv.x + bv.x;
  o.y = (v.y - mu) * rstd * gv.y + bv.y;
  o.z = (v.z - mu) * rstd * gv.z + bv.z;
  o.w = (v.w - mu) * rstd * gv.w + bv.w;
  *(float4*)(out + (size_t)row * 1024 + t * 4) = o;
}

// ---------------- launch ----------------

extern "C" void kernel_launch(void* const* d_in, const int* in_sizes, int n_in,
                              void* d_out, int out_size, void* d_ws, size_t ws_size,
                              hipStream_t stream) {
  const float* w      = (const float*)d_in[0];
  const float* r_emb  = (const float*)d_in[1];
  const float* r_w_b  = (const float*)d_in[2];
  const float* r_bias = (const float*)d_in[3];
  // d_in[4] attn_mask: implemented analytically (causal)
  const float* W_qkv  = (const float*)d_in[5];
  const float* W_o    = (const float*)d_in[6];
  const float* ln_g   = (const float*)d_in[7];
  const float* ln_b   = (const float*)d_in[8];
  float* out = (float*)d_out;
  char* ws = (char*)d_ws;

  ushort_t* X16  = (ushort_t*)(ws + 0);          //  8,388,608 B  x bf16
  ushort_t* WQ16 = (ushort_t*)(ws + 8388608);    //  6,291,456 B  Wqkv^T bf16 [3072][1024]
  ushort_t* WO16 = (ushort_t*)(ws + 14680064);   //  2,097,152 B  Wo^T bf16 [1024][1024]
  ushort_t* RE16 = (ushort_t*)(ws + 16777216);   //  4,194,304 B  r_emb bf16 [h][r][d]
  float*    RB2  = (float*)(ws + 20971520);      //    131,072 B  rbias2[h][r] (pre-scaled)
  ushort_t* QT16 = (ushort_t*)(ws + 21102592);   //  8,388,608 B  q~ bf16 [b][h][i][d] (pre-scaled)
  ushort_t* K16  = (ushort_t*)(ws + 29491200);   //  8,388,608 B  [b][h][i][d]
  ushort_t* VT16 = (ushort_t*)(ws + 37879808);   //  8,388,608 B  V^T [b][h][d][j]
  ushort_t* AV16 = (ushort_t*)(ws + 46268416);   //  8,388,608 B  attn_vec bf16 [4096][1024]
  float*    Y32  = (float*)(ws + 54657024);      // 16,777,216 B  y fp32

  k_conv_x<<<4096, 256, 0, stream>>>(w, X16);
  k_transpose_bf16<<<dim3(96, 32), dim3(32, 8), 0, stream>>>(W_qkv, WQ16, 1024, 3072);
  k_transpose_bf16<<<dim3(32, 32), dim3(32, 8), 0, stream>>>(W_o, WO16, 1024, 1024);
  k_conv_remb<<<1024, 256, 0, stream>>>(r_emb, RE16);
  k_rbias2<<<128, 256, 0, stream>>>(RE16, r_w_b, r_bias, RB2);
  k_gemm_qkv<<<dim3(32, 24), 256, 0, stream>>>(X16, WQ16, r_w_b, QT16, K16, VT16);
  k_flash<<<dim3(32, 32), 256, 0, stream>>>(QT16, K16, VT16, RE16, RB2, AV16);
  k_gemm_o<<<dim3(32, 8), 256, 0, stream>>>(AV16, WO16, w, Y32);
  k_ln<<<4096, 256, 0, stream>>>(Y32, ln_g, ln_b, out);
}

// Round 14
// 175.248 us; speedup vs baseline: 1.8083x; 1.0252x over previous
//
#include <hip/hip_runtime.h>

typedef unsigned short ushort_t;
typedef unsigned short us4 __attribute__((ext_vector_type(4)));
typedef unsigned short us8 __attribute__((ext_vector_type(8)));
typedef unsigned int   u32x4 __attribute__((ext_vector_type(4)));
typedef float          f32x4 __attribute__((ext_vector_type(4)));
typedef __bf16         bf16x8 __attribute__((ext_vector_type(8)));

// SCALE2 = 0.125 * log2(e): softmax computed in base-2 (v_exp_f32 is 2^x)
#define SCALE2 0.18033688011112042f

__device__ __forceinline__ unsigned short f2bf(float f) {
  unsigned u = __builtin_bit_cast(unsigned, f);
  u += 0x7fffu + ((u >> 16) & 1u);
  return (unsigned short)(u >> 16);
}
__device__ __forceinline__ float bf2f(unsigned short h) {
  unsigned u = ((unsigned)h) << 16;
  return __builtin_bit_cast(float, u);
}

// async 16B global -> LDS (wave-uniform LDS base + lane*16; lane-linear here)
__device__ __forceinline__ void async_cp16(const ushort_t* g, ushort_t* l) {
  __builtin_amdgcn_global_load_lds(
      (const __attribute__((address_space(1))) unsigned int*)g,
      (__attribute__((address_space(3))) unsigned int*)l, 16, 0, 0);
}

// DPP row-rotate (16-lane row) — VALU-pipe cross-lane, replaces ds_bpermute
template <int CTRL>
__device__ __forceinline__ float dpp_rotf(float x) {
  return __builtin_bit_cast(float,
      __builtin_amdgcn_update_dpp(0, __builtin_bit_cast(int, x), CTRL, 0xF, 0xF, true));
}
// 16-lane reduction via row_ror 1,2,4,8 (covers all 16 lanes, any commutative op)
__device__ __forceinline__ float row16_max(float x) {
  x = fmaxf(x, dpp_rotf<0x121>(x));
  x = fmaxf(x, dpp_rotf<0x122>(x));
  x = fmaxf(x, dpp_rotf<0x124>(x));
  x = fmaxf(x, dpp_rotf<0x128>(x));
  return x;
}
__device__ __forceinline__ float row16_sum(float x) {
  x += dpp_rotf<0x121>(x);
  x += dpp_rotf<0x122>(x);
  x += dpp_rotf<0x124>(x);
  x += dpp_rotf<0x128>(x);
  return x;
}

// ---------------- prep kernels ----------------

__global__ __launch_bounds__(256) void k_conv_x(const float* __restrict__ in,
                                                ushort_t* __restrict__ out) {
  int i = (blockIdx.x * 256 + threadIdx.x) * 4;
  float4 v = *(const float4*)(in + i);
  us4 o;
  o[0] = f2bf(v.x); o[1] = f2bf(v.y); o[2] = f2bf(v.z); o[3] = f2bf(v.w);
  *(us4*)(out + i) = o;
}

// in[R][C] f32 -> out[C][R] bf16
__global__ __launch_bounds__(256) void k_transpose_bf16(const float* __restrict__ in,
                                                        ushort_t* __restrict__ out,
                                                        int R, int C) {
  __shared__ float tile[32][33];
  int c0 = blockIdx.x * 32, r0 = blockIdx.y * 32;
  int tx = threadIdx.x, ty = threadIdx.y;
#pragma unroll
  for (int k = 0; k < 32; k += 8)
    tile[ty + k][tx] = in[(size_t)(r0 + ty + k) * C + c0 + tx];
  __syncthreads();
#pragma unroll
  for (int k = 0; k < 32; k += 8)
    out[(size_t)(c0 + ty + k) * R + r0 + tx] = f2bf(tile[tx][ty + k]);
}

// r_emb (r, h, d) f32 -> RE16 [h][r][d] bf16
__global__ __launch_bounds__(256) void k_conv_remb(const float* __restrict__ re,
                                                   ushort_t* __restrict__ out) {
  int tid = blockIdx.x * 256 + threadIdx.x;
  int o = tid * 8;
  int d = o & 63, r = (o >> 6) & 2047, h = o >> 17;
  const float* src = re + ((size_t)r * 16 + h) * 64 + d;
  float4 a = *(const float4*)(src);
  float4 b = *(const float4*)(src + 4);
  us8 u;
  u[0] = f2bf(a.x); u[1] = f2bf(a.y); u[2] = f2bf(a.z); u[3] = f2bf(a.w);
  u[4] = f2bf(b.x); u[5] = f2bf(b.y); u[6] = f2bf(b.z); u[7] = f2bf(b.w);
  *(us8*)(out + o) = u;
}

// rbias2[h][r] = (r_bias[r][h] - dot(r_w_bias[h], r_emb_bf16[h][r])) * SCALE2
__global__ __launch_bounds__(256) void k_rbias2(const ushort_t* __restrict__ RE,
                                                const float* __restrict__ rwb,
                                                const float* __restrict__ rbias,
                                                float* __restrict__ out) {
  int tid = blockIdx.x * 256 + threadIdx.x;  // 32768 total
  int h = tid >> 11, r = tid & 2047;
  const ushort_t* re = RE + ((size_t)h * 2048 + r) * 64;
  const float* wv = rwb + h * 64;
  float acc = 0.f;
#pragma unroll
  for (int d0 = 0; d0 < 64; d0 += 8) {
    us8 v = *(const us8*)(re + d0);
#pragma unroll
    for (int e = 0; e < 8; ++e) acc += bf2f(v[e]) * wv[d0 + e];
  }
  out[h * 2048 + r] = (rbias[r * 16 + h] - acc) * SCALE2;
}

// ---------------- GEMM 1: X(4096x1024) @ Wqkv -> scatter q~,k,v^T ----------------

__global__ __launch_bounds__(256) void k_gemm_qkv(const ushort_t* __restrict__ A,
                                                  const ushort_t* __restrict__ B,
                                                  const float* __restrict__ rwb,
                                                  ushort_t* __restrict__ qt,
                                                  ushort_t* __restrict__ kk,
                                                  ushort_t* __restrict__ vv) {
  __shared__ ushort_t Al[128 * 32], Bl[128 * 32];
  int row0 = blockIdx.x * 128, col0 = blockIdx.y * 128;
  int t = threadIdx.x, w = t >> 6, l = t & 63;
  int wr = w >> 1, wc = w & 1, g = l >> 4, cl = l & 15;
  f32x4 acc[4][4];
#pragma unroll
  for (int m = 0; m < 4; ++m)
#pragma unroll
    for (int n = 0; n < 4; ++n) acc[m][n] = (f32x4){0.f, 0.f, 0.f, 0.f};
  for (int k0 = 0; k0 < 1024; k0 += 32) {
#pragma unroll
    for (int c = 0; c < 2; ++c) {
      int u = t + 256 * c, row = u >> 2, col = (u & 3) * 8;
      async_cp16(A + (size_t)(row0 + row) * 1024 + k0 + col, &Al[u * 8]);
      async_cp16(B + (size_t)(col0 + row) * 1024 + k0 + col, &Bl[u * 8]);
    }
    __syncthreads();
    bf16x8 af[4], bfr[4];
#pragma unroll
    for (int m = 0; m < 4; ++m) af[m] = *(const bf16x8*)(&Al[(wr * 64 + m * 16 + cl) * 32 + g * 8]);
#pragma unroll
    for (int n = 0; n < 4; ++n) bfr[n] = *(const bf16x8*)(&Bl[(wc * 64 + n * 16 + cl) * 32 + g * 8]);
#pragma unroll
    for (int m = 0; m < 4; ++m)
#pragma unroll
      for (int n = 0; n < 4; ++n)
        acc[m][n] = __builtin_amdgcn_mfma_f32_16x16x32_bf16(af[m], bfr[n], acc[m][n], 0, 0, 0);
    __syncthreads();
  }
  int sec = col0 >> 10;  // block-uniform: 0=q,1=k,2=v
#pragma unroll
  for (int m = 0; m < 4; ++m) {
#pragma unroll
    for (int n = 0; n < 4; ++n) {
#pragma unroll
      for (int r = 0; r < 4; ++r) {
        int row = row0 + wr * 64 + m * 16 + g * 4 + r;
        int col = col0 + wc * 64 + n * 16 + cl;
        int mm = col & 1023, hh = mm >> 6, d = mm & 63;
        int bq = row & 1, iq = row >> 1;
        float val = acc[m][n][r];
        if (sec == 0) {
          qt[(((size_t)bq * 16 + hh) * 2048 + iq) * 64 + d] = f2bf((val + rwb[mm]) * SCALE2);
        } else if (sec == 1) {
          kk[(((size_t)bq * 16 + hh) * 2048 + iq) * 64 + d] = f2bf(val);
        } else {
          // V stored transposed: [b][h][d][j]
          vv[(((size_t)bq * 16 + hh) * 64 + d) * 2048 + iq] = f2bf(val);
        }
      }
    }
  }
}

// ---------------- flash attention with rel-pos band (R11-green verbatim,
// softmax in base-2: exp2f, scales pre-folded with log2e) ----------------

__global__ __launch_bounds__(256, 3) void k_flash(const ushort_t* __restrict__ QT,
                                                  const ushort_t* __restrict__ KK,
                                                  const ushort_t* __restrict__ VT,
                                                  const ushort_t* __restrict__ RE,
                                                  const float* __restrict__ RB2,
                                                  ushort_t* __restrict__ AV) {
  int bh = blockIdx.x, b = bh >> 4, h = bh & 15;
  int i0 = (gridDim.y - 1 - blockIdx.y) * 64;  // longest blocks first
  int t = threadIdx.x, w = t >> 6, l = t & 63, g = l >> 4, cl = l & 15;

  __shared__ ushort_t Klds[64 * 72];   //  9216 B
  __shared__ ushort_t Vt[64 * 72];     //  9216 B  (V^T tile: rows d, cols j)
  __shared__ ushort_t Rl[128 * 72];    // 18432 B  circular by (global_r & 127)
  __shared__ float rb2s[128];          //   512 B  circular
  __shared__ ushort_t Pls[4][16 * 76]; //  9728 B  P bf16 (wave-private, padded stride)
  __shared__ float alphal[4][16];
  __shared__ float lsuml[4][16];
  // total ~47.6 KiB -> 3 blocks/CU

  const ushort_t* qb = QT + ((size_t)(b * 16 + h)) * 2048 * 64;
  const ushort_t* kb = KK + ((size_t)(b * 16 + h)) * 2048 * 64;
  const ushort_t* vt = VT + ((size_t)(b * 16 + h)) * 64 * 2048;
  const ushort_t* rbase = RE + (size_t)h * 2048 * 64;
  const float* r2 = RB2 + h * 2048;

  int qrow = i0 + w * 16 + cl;
  bf16x8 qa0 = *(const bf16x8*)(qb + (size_t)qrow * 64 + g * 8);
  bf16x8 qa1 = *(const bf16x8*)(qb + (size_t)qrow * 64 + 32 + g * 8);

  float m_run[4], l_run[4];
  f32x4 Ot[4];
#pragma unroll
  for (int r = 0; r < 4; ++r) { m_run[r] = -1e30f; l_run[r] = 0.f; }
#pragma unroll
  for (int dt = 0; dt < 4; ++dt) Ot[dt] = (f32x4){0.f, 0.f, 0.f, 0.f};

  int nt = gridDim.y - blockIdx.y;  // = i0/64 + 1
  int rb0f = 1984 - i0;
  int urow = t >> 3, ucol = (t & 7) * 8;

  // preload bottom 64 band rows of tile 0 (rows rb0f..rb0f+63, always < 2048)
  *(u32x4*)(&Rl[((rb0f + urow) & 127) * 72 + ucol]) =
      *(const u32x4*)(rbase + (size_t)(rb0f + urow) * 64 + ucol);
  *(u32x4*)(&Rl[((rb0f + urow + 32) & 127) * 72 + ucol]) =
      *(const u32x4*)(rbase + (size_t)(rb0f + urow + 32) * 64 + ucol);
  if (t < 64) rb2s[(rb0f + t) & 127] = r2[rb0f + t];

  // pipeline registers
  u32x4 kreg0, kreg1, vreg0, vreg1, rreg0, rreg1;
  float rb2reg;

  // issue loads for tile 0
  {
    kreg0 = *(const u32x4*)(kb + (size_t)urow * 64 + ucol);
    kreg1 = *(const u32x4*)(kb + (size_t)(urow + 32) * 64 + ucol);
    vreg0 = *(const u32x4*)(vt + (size_t)urow * 2048 + ucol);
    vreg1 = *(const u32x4*)(vt + (size_t)(urow + 32) * 2048 + ucol);
    int gs = rb0f + 64;
    int rr0 = gs + urow, rr1 = gs + urow + 32;
    rreg0 = (rr0 < 2048) ? *(const u32x4*)(rbase + (size_t)rr0 * 64 + ucol) : (u32x4){0u, 0u, 0u, 0u};
    rreg1 = (rr1 < 2048) ? *(const u32x4*)(rbase + (size_t)rr1 * 64 + ucol) : (u32x4){0u, 0u, 0u, 0u};
    int rrb = gs + t;
    rb2reg = (t < 64 && rrb < 2048) ? r2[rrb] : 0.f;
  }

  for (int tt = 0; tt < nt; ++tt) {
    int j0 = tt * 64;
    int rb0 = rb0f + j0;
    __syncthreads();  // (A) previous tile's compute done; LDS free
    // write staged regs -> LDS
    {
      *(u32x4*)(&Klds[urow * 72 + ucol]) = kreg0;
      *(u32x4*)(&Klds[(urow + 32) * 72 + ucol]) = kreg1;
      *(u32x4*)(&Vt[urow * 72 + ucol]) = vreg0;
      *(u32x4*)(&Vt[(urow + 32) * 72 + ucol]) = vreg1;
      int gs = rb0 + 64;
      *(u32x4*)(&Rl[((gs + urow) & 127) * 72 + ucol]) = rreg0;
      *(u32x4*)(&Rl[((gs + urow + 32) & 127) * 72 + ucol]) = rreg1;
      if (t < 64) rb2s[(gs + t) & 127] = rb2reg;
    }
    __syncthreads();  // (B) staging visible
    // issue next tile's loads (hide latency under compute)
    if (tt + 1 < nt) {
      int j0n = j0 + 64;
      kreg0 = *(const u32x4*)(kb + (size_t)(j0n + urow) * 64 + ucol);
      kreg1 = *(const u32x4*)(kb + (size_t)(j0n + urow + 32) * 64 + ucol);
      vreg0 = *(const u32x4*)(vt + (size_t)urow * 2048 + j0n + ucol);
      vreg1 = *(const u32x4*)(vt + (size_t)(urow + 32) * 2048 + j0n + ucol);
      int gs = rb0f + j0n + 64;
      int rr0 = gs + urow, rr1 = gs + urow + 32;
      rreg0 = (rr0 < 2048) ? *(const u32x4*)(rbase + (size_t)rr0 * 64 + ucol) : (u32x4){0u, 0u, 0u, 0u};
      rreg1 = (rr1 < 2048) ? *(const u32x4*)(rbase + (size_t)rr1 * 64 + ucol) : (u32x4){0u, 0u, 0u, 0u};
      int rrb = gs + t;
      rb2reg = (t < 64 && rrb < 2048) ? r2[rrb] : 0.f;
    }

    // ---- Bw: q~ strip (16x64) @ R_band^T -> 16x80, kept in REGISTERS ----
    int bw0 = 48 - 16 * w;
    int rB = rb0 + bw0;
    f32x4 bwf[5];
    __builtin_amdgcn_s_setprio(1);
#pragma unroll
    for (int ct = 0; ct < 5; ++ct) {
      int prow = (rB + ct * 16) & 127;  // multiple of 16
      f32x4 a = (f32x4){0.f, 0.f, 0.f, 0.f};
      bf16x8 rr0 = *(const bf16x8*)(&Rl[(prow + cl) * 72 + g * 8]);
      a = __builtin_amdgcn_mfma_f32_16x16x32_bf16(qa0, rr0, a, 0, 0, 0);
      bf16x8 rr1 = *(const bf16x8*)(&Rl[(prow + cl) * 72 + 32 + g * 8]);
      a = __builtin_amdgcn_mfma_f32_16x16x32_bf16(qa1, rr1, a, 0, 0, 0);
      float rv = rb2s[(prow + cl) & 127];  // same circular slot as the R row
      a[0] += rv; a[1] += rv; a[2] += rv; a[3] += rv;
      bwf[ct] = a;
    }

    // ---- AC = q~ @ K^T ----
    f32x4 S[4];
#pragma unroll
    for (int ct = 0; ct < 4; ++ct) {
      f32x4 a = (f32x4){0.f, 0.f, 0.f, 0.f};
      bf16x8 kf0 = *(const bf16x8*)(&Klds[(ct * 16 + cl) * 72 + g * 8]);
      a = __builtin_amdgcn_mfma_f32_16x16x32_bf16(qa0, kf0, a, 0, 0, 0);
      bf16x8 kf1 = *(const bf16x8*)(&Klds[(ct * 16 + cl) * 72 + 32 + g * 8]);
      a = __builtin_amdgcn_mfma_f32_16x16x32_bf16(qa1, kf1, a, 0, 0, 0);
      S[ct] = a;
    }
    __builtin_amdgcn_s_setprio(0);

    // ---- scores + mask (diag tile only) + online softmax (base-2, DPP) ----
    bool diag = (tt == nt - 1);
    int climit = i0 - j0 + 15 + 16 * w;
#pragma unroll
    for (int r = 0; r < 4; ++r) {
      int rl = g * 4 + r;
      int dlt = cl - rl + 15;               // in [0,30]
      int src = (l & 48) | (dlt & 15);
      float b0 = __shfl(bwf[0][r], src);
      float b1 = __shfl(bwf[1][r], src);
      float b2 = __shfl(bwf[2][r], src);
      float b3 = __shfl(bwf[3][r], src);
      float b4 = __shfl(bwf[4][r], src);
      if (dlt >= 16) { b0 = b1; b1 = b2; b2 = b3; b3 = b4; }
      float sv[4];
      if (diag) {
        sv[0] = (dlt      <= climit) ? S[0][r] + b0 : -1e30f;
        sv[1] = (dlt + 16 <= climit) ? S[1][r] + b1 : -1e30f;
        sv[2] = (dlt + 32 <= climit) ? S[2][r] + b2 : -1e30f;
        sv[3] = (dlt + 48 <= climit) ? S[3][r] + b3 : -1e30f;
      } else {
        sv[0] = S[0][r] + b0;
        sv[1] = S[1][r] + b1;
        sv[2] = S[2][r] + b2;
        sv[3] = S[3][r] + b3;
      }
      float rmax = fmaxf(fmaxf(sv[0], sv[1]), fmaxf(sv[2], sv[3]));
      rmax = row16_max(rmax);                 // DPP, VALU pipe
      float mn = fmaxf(m_run[r], rmax);
      float al = exp2f(m_run[r] - mn);        // base-2 (v_exp_f32 native)
      m_run[r] = mn;
      float rsum = 0.f;
#pragma unroll
      for (int ct = 0; ct < 4; ++ct) {
        float pv = exp2f(sv[ct] - mn);
        sv[ct] = pv;
        rsum += pv;
      }
      rsum = row16_sum(rsum);                 // DPP, VALU pipe
      l_run[r] = l_run[r] * al + rsum;
      if (cl == 0) alphal[w][rl] = al;
#pragma unroll
      for (int ct = 0; ct < 4; ++ct)
        Pls[w][rl * 76 + ct * 16 + cl] = f2bf(sv[ct]);
    }
    // no barrier: Pls/alphal wave-private; same-wave DS ops program-ordered

    // ---- O^T += V^T @ P^T ----
    float aq = alphal[w][cl];
    bf16x8 pb0 = *(const bf16x8*)(&Pls[w][cl * 76 + g * 8]);
    bf16x8 pb1 = *(const bf16x8*)(&Pls[w][cl * 76 + 32 + g * 8]);
    __builtin_amdgcn_s_setprio(1);
#pragma unroll
    for (int dt = 0; dt < 4; ++dt) {
      f32x4 o = Ot[dt];
      o[0] *= aq; o[1] *= aq; o[2] *= aq; o[3] *= aq;
      bf16x8 va0 = *(const bf16x8*)(&Vt[(dt * 16 + cl) * 72 + g * 8]);
      o = __builtin_amdgcn_mfma_f32_16x16x32_bf16(va0, pb0, o, 0, 0, 0);
      bf16x8 va1 = *(const bf16x8*)(&Vt[(dt * 16 + cl) * 72 + 32 + g * 8]);
      o = __builtin_amdgcn_mfma_f32_16x16x32_bf16(va1, pb1, o, 0, 0, 0);
      Ot[dt] = o;
    }
    __builtin_amdgcn_s_setprio(0);
  }

  if (cl == 0) {
#pragma unroll
    for (int r = 0; r < 4; ++r) lsuml[w][g * 4 + r] = l_run[r];
  }
  float inv = 1.f / lsuml[w][cl];
  int orow = (i0 + w * 16 + cl) * 2 + b;
#pragma unroll
  for (int dt = 0; dt < 4; ++dt) {
    us4 o4;
    o4[0] = f2bf(Ot[dt][0] * inv);
    o4[1] = f2bf(Ot[dt][1] * inv);
    o4[2] = f2bf(Ot[dt][2] * inv);
    o4[3] = f2bf(Ot[dt][3] * inv);
    *(us4*)(&AV[(size_t)orow * 1024 + h * 64 + dt * 16 + g * 4]) = o4;
  }
}

// ---------------- GEMM 2: attn_vec @ W_o + w -> Y ----------------

__global__ __launch_bounds__(256) void k_gemm_o(const ushort_t* __restrict__ A,
                                                const ushort_t* __restrict__ B,
                                                const float* __restrict__ wsrc,
                                                float* __restrict__ Y) {
  __shared__ ushort_t Al[128 * 32], Bl[128 * 32];
  int row0 = blockIdx.x * 128, col0 = blockIdx.y * 128;
  int t = threadIdx.x, w = t >> 6, l = t & 63;
  int wr = w >> 1, wc = w & 1, g = l >> 4, cl = l & 15;
  f32x4 acc[4][4];
#pragma unroll
  for (int m = 0; m < 4; ++m)
#pragma unroll
    for (int n = 0; n < 4; ++n) acc[m][n] = (f32x4){0.f, 0.f, 0.f, 0.f};
  for (int k0 = 0; k0 < 1024; k0 += 32) {
#pragma unroll
    for (int c = 0; c < 2; ++c) {
      int u = t + 256 * c, row = u >> 2, col = (u & 3) * 8;
      async_cp16(A + (size_t)(row0 + row) * 1024 + k0 + col, &Al[u * 8]);
      async_cp16(B + (size_t)(col0 + row) * 1024 + k0 + col, &Bl[u * 8]);
    }
    __syncthreads();
    bf16x8 af[4], bfr[4];
#pragma unroll
    for (int m = 0; m < 4; ++m) af[m] = *(const bf16x8*)(&Al[(wr * 64 + m * 16 + cl) * 32 + g * 8]);
#pragma unroll
    for (int n = 0; n < 4; ++n) bfr[n] = *(const bf16x8*)(&Bl[(wc * 64 + n * 16 + cl) * 32 + g * 8]);
#pragma unroll
    for (int m = 0; m < 4; ++m)
#pragma unroll
      for (int n = 0; n < 4; ++n)
        acc[m][n] = __builtin_amdgcn_mfma_f32_16x16x32_bf16(af[m], bfr[n], acc[m][n], 0, 0, 0);
    __syncthreads();
  }
#pragma unroll
  for (int m = 0; m < 4; ++m) {
#pragma unroll
    for (int n = 0; n < 4; ++n) {
#pragma unroll
      for (int r = 0; r < 4; ++r) {
        int row = row0 + wr * 64 + m * 16 + g * 4 + r;
        int col = col0 + wc * 64 + n * 16 + cl;
        size_t idx = (size_t)row * 1024 + col;
        Y[idx] = acc[m][n][r] + wsrc[idx];
      }
    }
  }
}

// ---------------- LayerNorm ----------------

__global__ __launch_bounds__(256) void k_ln(const float* __restrict__ Y,
                                            const float* __restrict__ gg,
                                            const float* __restrict__ bb,
                                            float* __restrict__ out) {
  int row = blockIdx.x, t = threadIdx.x;
  float4 v = *(const float4*)(Y + (size_t)row * 1024 + t * 4);
  float s = v.x + v.y + v.z + v.w;
  float q = v.x * v.x + v.y * v.y + v.z * v.z + v.w * v.w;
#pragma unroll
  for (int m = 32; m >= 1; m >>= 1) {
    s += __shfl_xor(s, m);
    q += __shfl_xor(q, m);
  }
  __shared__ float ssh[4], qsh[4];
  int w = t >> 6, l = t & 63;
  if (l == 0) { ssh[w] = s; qsh[w] = q; }
  __syncthreads();
  s = ssh[0] + ssh[1] + ssh[2] + ssh[3];
  q = qsh[0] + qsh[1] + qsh[2] + qsh[3];
  float mu = s * (1.f / 1024.f);
  float var = q * (1.f / 1024.f) - mu * mu;
  float rstd = rsqrtf(var + 1e-5f);
  float4 gv = *(const float4*)(gg + t * 4);
  float4 bv = *(const float4*)(bb + t * 4);
  float4 o;
  o.x = (v.x - mu) * rstd * gv.x + bv.x;
  o.y = (v.y - mu) * rstd * gv.y + bv.y;
  o.z = (v.z - mu) * rstd * gv.z + bv.z;
  o.w = (v.w - mu) * rstd * gv.w + bv.w;
  *(float4*)(out + (size_t)row * 1024 + t * 4) = o;
}

// ---------------- launch ----------------

extern "C" void kernel_launch(void* const* d_in, const int* in_sizes, int n_in,
                              void* d_out, int out_size, void* d_ws, size_t ws_size,
                              hipStream_t stream) {
  const float* w      = (const float*)d_in[0];
  const float* r_emb  = (const float*)d_in[1];
  const float* r_w_b  = (const float*)d_in[2];
  const float* r_bias = (const float*)d_in[3];
  // d_in[4] attn_mask: implemented analytically (causal)
  const float* W_qkv  = (const float*)d_in[5];
  const float* W_o    = (const float*)d_in[6];
  const float* ln_g   = (const float*)d_in[7];
  const float* ln_b   = (const float*)d_in[8];
  float* out = (float*)d_out;
  char* ws = (char*)d_ws;

  ushort_t* X16  = (ushort_t*)(ws + 0);          //  8,388,608 B  x bf16
  ushort_t* WQ16 = (ushort_t*)(ws + 8388608);    //  6,291,456 B  Wqkv^T bf16 [3072][1024]
  ushort_t* WO16 = (ushort_t*)(ws + 14680064);   //  2,097,152 B  Wo^T bf16 [1024][1024]
  ushort_t* RE16 = (ushort_t*)(ws + 16777216);   //  4,194,304 B  r_emb bf16 [h][r][d]
  float*    RB2  = (float*)(ws + 20971520);      //    131,072 B  rbias2[h][r] (pre-scaled, base-2)
  ushort_t* QT16 = (ushort_t*)(ws + 21102592);   //  8,388,608 B  q~ bf16 [b][h][i][d] (pre-scaled, base-2)
  ushort_t* K16  = (ushort_t*)(ws + 29491200);   //  8,388,608 B  [b][h][i][d]
  ushort_t* VT16 = (ushort_t*)(ws + 37879808);   //  8,388,608 B  V^T [b][h][d][j]
  ushort_t* AV16 = (ushort_t*)(ws + 46268416);   //  8,388,608 B  attn_vec bf16 [4096][1024]
  float*    Y32  = (float*)(ws + 54657024);      // 16,777,216 B  y fp32

  k_conv_x<<<4096, 256, 0, stream>>>(w, X16);
  k_transpose_bf16<<<dim3(96, 32), dim3(32, 8), 0, stream>>>(W_qkv, WQ16, 1024, 3072);
  k_transpose_bf16<<<dim3(32, 32), dim3(32, 8), 0, stream>>>(W_o, WO16, 1024, 1024);
  k_conv_remb<<<1024, 256, 0, stream>>>(r_emb, RE16);
  k_rbias2<<<128, 256, 0, stream>>>(RE16, r_w_b, r_bias, RB2);
  k_gemm_qkv<<<dim3(32, 24), 256, 0, stream>>>(X16, WQ16, r_w_b, QT16, K16, VT16);
  k_flash<<<dim3(32, 32), 256, 0, stream>>>(QT16, K16, VT16, RE16, RB2, AV16);
  k_gemm_o<<<dim3(32, 8), 256, 0, stream>>>(AV16, WO16, w, Y32);
  k_ln<<<4096, 256, 0, stream>>>(Y32, ln_g, ln_b, out);
}

// Round 15
// 171.574 us; speedup vs baseline: 1.8470x; 1.0214x over previous
//
#include <hip/hip_runtime.h>

typedef unsigned short ushort_t;
typedef unsigned short us4 __attribute__((ext_vector_type(4)));
typedef unsigned short us8 __attribute__((ext_vector_type(8)));
typedef unsigned int   u32x4 __attribute__((ext_vector_type(4)));
typedef float          f32x4 __attribute__((ext_vector_type(4)));
typedef __bf16         bf16x8 __attribute__((ext_vector_type(8)));

// SCALE2 = 0.125 * log2(e): softmax computed in base-2 (v_exp_f32 is 2^x)
#define SCALE2 0.18033688011112042f

__device__ __forceinline__ unsigned short f2bf(float f) {
  unsigned u = __builtin_bit_cast(unsigned, f);
  u += 0x7fffu + ((u >> 16) & 1u);
  return (unsigned short)(u >> 16);
}
__device__ __forceinline__ float bf2f(unsigned short h) {
  unsigned u = ((unsigned)h) << 16;
  return __builtin_bit_cast(float, u);
}

// raw v_exp_f32 (2^x), one instruction; compiler handles TRANS hazards
__device__ __forceinline__ float fast_exp2(float x) {
  return __builtin_amdgcn_exp2f(x);
}

// async 16B global -> LDS (wave-uniform LDS base + lane*16; lane-linear here)
__device__ __forceinline__ void async_cp16(const ushort_t* g, ushort_t* l) {
  __builtin_amdgcn_global_load_lds(
      (const __attribute__((address_space(1))) unsigned int*)g,
      (__attribute__((address_space(3))) unsigned int*)l, 16, 0, 0);
}

// DPP row-rotate (16-lane row) — VALU-pipe cross-lane, replaces ds_bpermute
template <int CTRL>
__device__ __forceinline__ float dpp_rotf(float x) {
  return __builtin_bit_cast(float,
      __builtin_amdgcn_update_dpp(0, __builtin_bit_cast(int, x), CTRL, 0xF, 0xF, true));
}
// 16-lane reduction via row_ror 1,2,4,8 (covers all 16 lanes, any commutative op)
__device__ __forceinline__ float row16_max(float x) {
  x = fmaxf(x, dpp_rotf<0x121>(x));
  x = fmaxf(x, dpp_rotf<0x122>(x));
  x = fmaxf(x, dpp_rotf<0x124>(x));
  x = fmaxf(x, dpp_rotf<0x128>(x));
  return x;
}
__device__ __forceinline__ float row16_sum(float x) {
  x += dpp_rotf<0x121>(x);
  x += dpp_rotf<0x122>(x);
  x += dpp_rotf<0x124>(x);
  x += dpp_rotf<0x128>(x);
  return x;
}

// ---------------- prep kernels ----------------

__global__ __launch_bounds__(256) void k_conv_x(const float* __restrict__ in,
                                                ushort_t* __restrict__ out) {
  int i = (blockIdx.x * 256 + threadIdx.x) * 4;
  float4 v = *(const float4*)(in + i);
  us4 o;
  o[0] = f2bf(v.x); o[1] = f2bf(v.y); o[2] = f2bf(v.z); o[3] = f2bf(v.w);
  *(us4*)(out + i) = o;
}

// in[R][C] f32 -> out[C][R] bf16
__global__ __launch_bounds__(256) void k_transpose_bf16(const float* __restrict__ in,
                                                        ushort_t* __restrict__ out,
                                                        int R, int C) {
  __shared__ float tile[32][33];
  int c0 = blockIdx.x * 32, r0 = blockIdx.y * 32;
  int tx = threadIdx.x, ty = threadIdx.y;
#pragma unroll
  for (int k = 0; k < 32; k += 8)
    tile[ty + k][tx] = in[(size_t)(r0 + ty + k) * C + c0 + tx];
  __syncthreads();
#pragma unroll
  for (int k = 0; k < 32; k += 8)
    out[(size_t)(c0 + ty + k) * R + r0 + tx] = f2bf(tile[tx][ty + k]);
}

// r_emb (r, h, d) f32 -> RE16 [h][r][d] bf16
__global__ __launch_bounds__(256) void k_conv_remb(const float* __restrict__ re,
                                                   ushort_t* __restrict__ out) {
  int tid = blockIdx.x * 256 + threadIdx.x;
  int o = tid * 8;
  int d = o & 63, r = (o >> 6) & 2047, h = o >> 17;
  const float* src = re + ((size_t)r * 16 + h) * 64 + d;
  float4 a = *(const float4*)(src);
  float4 b = *(const float4*)(src + 4);
  us8 u;
  u[0] = f2bf(a.x); u[1] = f2bf(a.y); u[2] = f2bf(a.z); u[3] = f2bf(a.w);
  u[4] = f2bf(b.x); u[5] = f2bf(b.y); u[6] = f2bf(b.z); u[7] = f2bf(b.w);
  *(us8*)(out + o) = u;
}

// rbias2[h][r] = (r_bias[r][h] - dot(r_w_bias[h], r_emb_bf16[h][r])) * SCALE2
__global__ __launch_bounds__(256) void k_rbias2(const ushort_t* __restrict__ RE,
                                                const float* __restrict__ rwb,
                                                const float* __restrict__ rbias,
                                                float* __restrict__ out) {
  int tid = blockIdx.x * 256 + threadIdx.x;  // 32768 total
  int h = tid >> 11, r = tid & 2047;
  const ushort_t* re = RE + ((size_t)h * 2048 + r) * 64;
  const float* wv = rwb + h * 64;
  float acc = 0.f;
#pragma unroll
  for (int d0 = 0; d0 < 64; d0 += 8) {
    us8 v = *(const us8*)(re + d0);
#pragma unroll
    for (int e = 0; e < 8; ++e) acc += bf2f(v[e]) * wv[d0 + e];
  }
  out[h * 2048 + r] = (rbias[r * 16 + h] - acc) * SCALE2;
}

// ---------------- GEMM 1: X(4096x1024) @ Wqkv -> scatter q~,k,v^T ----------------

__global__ __launch_bounds__(256) void k_gemm_qkv(const ushort_t* __restrict__ A,
                                                  const ushort_t* __restrict__ B,
                                                  const float* __restrict__ rwb,
                                                  ushort_t* __restrict__ qt,
                                                  ushort_t* __restrict__ kk,
                                                  ushort_t* __restrict__ vv) {
  __shared__ ushort_t Al[128 * 32], Bl[128 * 32];
  int row0 = blockIdx.x * 128, col0 = blockIdx.y * 128;
  int t = threadIdx.x, w = t >> 6, l = t & 63;
  int wr = w >> 1, wc = w & 1, g = l >> 4, cl = l & 15;
  f32x4 acc[4][4];
#pragma unroll
  for (int m = 0; m < 4; ++m)
#pragma unroll
    for (int n = 0; n < 4; ++n) acc[m][n] = (f32x4){0.f, 0.f, 0.f, 0.f};
  for (int k0 = 0; k0 < 1024; k0 += 32) {
#pragma unroll
    for (int c = 0; c < 2; ++c) {
      int u = t + 256 * c, row = u >> 2, col = (u & 3) * 8;
      async_cp16(A + (size_t)(row0 + row) * 1024 + k0 + col, &Al[u * 8]);
      async_cp16(B + (size_t)(col0 + row) * 1024 + k0 + col, &Bl[u * 8]);
    }
    __syncthreads();
    bf16x8 af[4], bfr[4];
#pragma unroll
    for (int m = 0; m < 4; ++m) af[m] = *(const bf16x8*)(&Al[(wr * 64 + m * 16 + cl) * 32 + g * 8]);
#pragma unroll
    for (int n = 0; n < 4; ++n) bfr[n] = *(const bf16x8*)(&Bl[(wc * 64 + n * 16 + cl) * 32 + g * 8]);
#pragma unroll
    for (int m = 0; m < 4; ++m)
#pragma unroll
      for (int n = 0; n < 4; ++n)
        acc[m][n] = __builtin_amdgcn_mfma_f32_16x16x32_bf16(af[m], bfr[n], acc[m][n], 0, 0, 0);
    __syncthreads();
  }
  int sec = col0 >> 10;  // block-uniform: 0=q,1=k,2=v
#pragma unroll
  for (int m = 0; m < 4; ++m) {
#pragma unroll
    for (int n = 0; n < 4; ++n) {
#pragma unroll
      for (int r = 0; r < 4; ++r) {
        int row = row0 + wr * 64 + m * 16 + g * 4 + r;
        int col = col0 + wc * 64 + n * 16 + cl;
        int mm = col & 1023, hh = mm >> 6, d = mm & 63;
        int bq = row & 1, iq = row >> 1;
        float val = acc[m][n][r];
        if (sec == 0) {
          qt[(((size_t)bq * 16 + hh) * 2048 + iq) * 64 + d] = f2bf((val + rwb[mm]) * SCALE2);
        } else if (sec == 1) {
          kk[(((size_t)bq * 16 + hh) * 2048 + iq) * 64 + d] = f2bf(val);
        } else {
          // V stored transposed: [b][h][d][j]
          vv[(((size_t)bq * 16 + hh) * 64 + d) * 2048 + iq] = f2bf(val);
        }
      }
    }
  }
}

// ---------------- flash attention with rel-pos band (R11-green structure,
// softmax in base-2 via raw v_exp_f32; scales pre-folded with log2e) ----------------

__global__ __launch_bounds__(256, 3) void k_flash(const ushort_t* __restrict__ QT,
                                                  const ushort_t* __restrict__ KK,
                                                  const ushort_t* __restrict__ VT,
                                                  const ushort_t* __restrict__ RE,
                                                  const float* __restrict__ RB2,
                                                  ushort_t* __restrict__ AV) {
  int bh = blockIdx.x, b = bh >> 4, h = bh & 15;
  int i0 = (gridDim.y - 1 - blockIdx.y) * 64;  // longest blocks first
  int t = threadIdx.x, w = t >> 6, l = t & 63, g = l >> 4, cl = l & 15;

  __shared__ ushort_t Klds[64 * 72];   //  9216 B
  __shared__ ushort_t Vt[64 * 72];     //  9216 B  (V^T tile: rows d, cols j)
  __shared__ ushort_t Rl[128 * 72];    // 18432 B  circular by (global_r & 127)
  __shared__ float rb2s[128];          //   512 B  circular
  __shared__ ushort_t Pls[4][16 * 76]; //  9728 B  P bf16 (wave-private, padded stride)
  __shared__ float alphal[4][16];
  __shared__ float lsuml[4][16];
  // total ~47.6 KiB -> 3 blocks/CU

  const ushort_t* qb = QT + ((size_t)(b * 16 + h)) * 2048 * 64;
  const ushort_t* kb = KK + ((size_t)(b * 16 + h)) * 2048 * 64;
  const ushort_t* vt = VT + ((size_t)(b * 16 + h)) * 64 * 2048;
  const ushort_t* rbase = RE + (size_t)h * 2048 * 64;
  const float* r2 = RB2 + h * 2048;

  int qrow = i0 + w * 16 + cl;
  bf16x8 qa0 = *(const bf16x8*)(qb + (size_t)qrow * 64 + g * 8);
  bf16x8 qa1 = *(const bf16x8*)(qb + (size_t)qrow * 64 + 32 + g * 8);

  float m_run[4], l_run[4];
  f32x4 Ot[4];
#pragma unroll
  for (int r = 0; r < 4; ++r) { m_run[r] = -1e30f; l_run[r] = 0.f; }
#pragma unroll
  for (int dt = 0; dt < 4; ++dt) Ot[dt] = (f32x4){0.f, 0.f, 0.f, 0.f};

  int nt = gridDim.y - blockIdx.y;  // = i0/64 + 1
  int rb0f = 1984 - i0;
  int urow = t >> 3, ucol = (t & 7) * 8;

  // preload bottom 64 band rows of tile 0 (rows rb0f..rb0f+63, always < 2048)
  *(u32x4*)(&Rl[((rb0f + urow) & 127) * 72 + ucol]) =
      *(const u32x4*)(rbase + (size_t)(rb0f + urow) * 64 + ucol);
  *(u32x4*)(&Rl[((rb0f + urow + 32) & 127) * 72 + ucol]) =
      *(const u32x4*)(rbase + (size_t)(rb0f + urow + 32) * 64 + ucol);
  if (t < 64) rb2s[(rb0f + t) & 127] = r2[rb0f + t];

  // pipeline registers
  u32x4 kreg0, kreg1, vreg0, vreg1, rreg0, rreg1;
  float rb2reg;

  // issue loads for tile 0
  {
    kreg0 = *(const u32x4*)(kb + (size_t)urow * 64 + ucol);
    kreg1 = *(const u32x4*)(kb + (size_t)(urow + 32) * 64 + ucol);
    vreg0 = *(const u32x4*)(vt + (size_t)urow * 2048 + ucol);
    vreg1 = *(const u32x4*)(vt + (size_t)(urow + 32) * 2048 + ucol);
    int gs = rb0f + 64;
    int rr0 = gs + urow, rr1 = gs + urow + 32;
    rreg0 = (rr0 < 2048) ? *(const u32x4*)(rbase + (size_t)rr0 * 64 + ucol) : (u32x4){0u, 0u, 0u, 0u};
    rreg1 = (rr1 < 2048) ? *(const u32x4*)(rbase + (size_t)rr1 * 64 + ucol) : (u32x4){0u, 0u, 0u, 0u};
    int rrb = gs + t;
    rb2reg = (t < 64 && rrb < 2048) ? r2[rrb] : 0.f;
  }

  for (int tt = 0; tt < nt; ++tt) {
    int j0 = tt * 64;
    int rb0 = rb0f + j0;
    __syncthreads();  // (A) previous tile's compute done; LDS free
    // write staged regs -> LDS
    {
      *(u32x4*)(&Klds[urow * 72 + ucol]) = kreg0;
      *(u32x4*)(&Klds[(urow + 32) * 72 + ucol]) = kreg1;
      *(u32x4*)(&Vt[urow * 72 + ucol]) = vreg0;
      *(u32x4*)(&Vt[(urow + 32) * 72 + ucol]) = vreg1;
      int gs = rb0 + 64;
      *(u32x4*)(&Rl[((gs + urow) & 127) * 72 + ucol]) = rreg0;
      *(u32x4*)(&Rl[((gs + urow + 32) & 127) * 72 + ucol]) = rreg1;
      if (t < 64) rb2s[(gs + t) & 127] = rb2reg;
    }
    __syncthreads();  // (B) staging visible
    // issue next tile's loads (hide latency under compute)
    if (tt + 1 < nt) {
      int j0n = j0 + 64;
      kreg0 = *(const u32x4*)(kb + (size_t)(j0n + urow) * 64 + ucol);
      kreg1 = *(const u32x4*)(kb + (size_t)(j0n + urow + 32) * 64 + ucol);
      vreg0 = *(const u32x4*)(vt + (size_t)urow * 2048 + j0n + ucol);
      vreg1 = *(const u32x4*)(vt + (size_t)(urow + 32) * 2048 + j0n + ucol);
      int gs = rb0f + j0n + 64;
      int rr0 = gs + urow, rr1 = gs + urow + 32;
      rreg0 = (rr0 < 2048) ? *(const u32x4*)(rbase + (size_t)rr0 * 64 + ucol) : (u32x4){0u, 0u, 0u, 0u};
      rreg1 = (rr1 < 2048) ? *(const u32x4*)(rbase + (size_t)rr1 * 64 + ucol) : (u32x4){0u, 0u, 0u, 0u};
      int rrb = gs + t;
      rb2reg = (t < 64 && rrb < 2048) ? r2[rrb] : 0.f;
    }

    // ---- Bw: q~ strip (16x64) @ R_band^T -> 16x80, kept in REGISTERS ----
    int bw0 = 48 - 16 * w;
    int rB = rb0 + bw0;
    f32x4 bwf[5];
    __builtin_amdgcn_s_setprio(1);
#pragma unroll
    for (int ct = 0; ct < 5; ++ct) {
      int prow = (rB + ct * 16) & 127;  // multiple of 16
      f32x4 a = (f32x4){0.f, 0.f, 0.f, 0.f};
      bf16x8 rr0 = *(const bf16x8*)(&Rl[(prow + cl) * 72 + g * 8]);
      a = __builtin_amdgcn_mfma_f32_16x16x32_bf16(qa0, rr0, a, 0, 0, 0);
      bf16x8 rr1 = *(const bf16x8*)(&Rl[(prow + cl) * 72 + 32 + g * 8]);
      a = __builtin_amdgcn_mfma_f32_16x16x32_bf16(qa1, rr1, a, 0, 0, 0);
      float rv = rb2s[(prow + cl) & 127];  // same circular slot as the R row
      a[0] += rv; a[1] += rv; a[2] += rv; a[3] += rv;
      bwf[ct] = a;
    }

    // ---- AC = q~ @ K^T ----
    f32x4 S[4];
#pragma unroll
    for (int ct = 0; ct < 4; ++ct) {
      f32x4 a = (f32x4){0.f, 0.f, 0.f, 0.f};
      bf16x8 kf0 = *(const bf16x8*)(&Klds[(ct * 16 + cl) * 72 + g * 8]);
      a = __builtin_amdgcn_mfma_f32_16x16x32_bf16(qa0, kf0, a, 0, 0, 0);
      bf16x8 kf1 = *(const bf16x8*)(&Klds[(ct * 16 + cl) * 72 + 32 + g * 8]);
      a = __builtin_amdgcn_mfma_f32_16x16x32_bf16(qa1, kf1, a, 0, 0, 0);
      S[ct] = a;
    }
    __builtin_amdgcn_s_setprio(0);

    // ---- scores + mask (diag tile only) + online softmax (base-2, DPP) ----
    bool diag = (tt == nt - 1);
    int climit = i0 - j0 + 15 + 16 * w;
#pragma unroll
    for (int r = 0; r < 4; ++r) {
      int rl = g * 4 + r;
      int dlt = cl - rl + 15;               // in [0,30]
      int src = (l & 48) | (dlt & 15);
      float b0 = __shfl(bwf[0][r], src);
      float b1 = __shfl(bwf[1][r], src);
      float b2 = __shfl(bwf[2][r], src);
      float b3 = __shfl(bwf[3][r], src);
      float b4 = __shfl(bwf[4][r], src);
      if (dlt >= 16) { b0 = b1; b1 = b2; b2 = b3; b3 = b4; }
      float sv[4];
      if (diag) {
        sv[0] = (dlt      <= climit) ? S[0][r] + b0 : -1e30f;
        sv[1] = (dlt + 16 <= climit) ? S[1][r] + b1 : -1e30f;
        sv[2] = (dlt + 32 <= climit) ? S[2][r] + b2 : -1e30f;
        sv[3] = (dlt + 48 <= climit) ? S[3][r] + b3 : -1e30f;
      } else {
        sv[0] = S[0][r] + b0;
        sv[1] = S[1][r] + b1;
        sv[2] = S[2][r] + b2;
        sv[3] = S[3][r] + b3;
      }
      float rmax = fmaxf(fmaxf(sv[0], sv[1]), fmaxf(sv[2], sv[3]));
      rmax = row16_max(rmax);                 // DPP, VALU pipe
      float mn = fmaxf(m_run[r], rmax);
      float al = fast_exp2(m_run[r] - mn);    // single v_exp_f32
      m_run[r] = mn;
      float rsum = 0.f;
#pragma unroll
      for (int ct = 0; ct < 4; ++ct) {
        float pv = fast_exp2(sv[ct] - mn);    // single v_exp_f32
        sv[ct] = pv;
        rsum += pv;
      }
      rsum = row16_sum(rsum);                 // DPP, VALU pipe
      l_run[r] = l_run[r] * al + rsum;
      if (cl == 0) alphal[w][rl] = al;
#pragma unroll
      for (int ct = 0; ct < 4; ++ct)
        Pls[w][rl * 76 + ct * 16 + cl] = f2bf(sv[ct]);
    }
    // no barrier: Pls/alphal wave-private; same-wave DS ops program-ordered

    // ---- O^T += V^T @ P^T ----
    float aq = alphal[w][cl];
    bf16x8 pb0 = *(const bf16x8*)(&Pls[w][cl * 76 + g * 8]);
    bf16x8 pb1 = *(const bf16x8*)(&Pls[w][cl * 76 + 32 + g * 8]);
    __builtin_amdgcn_s_setprio(1);
#pragma unroll
    for (int dt = 0; dt < 4; ++dt) {
      f32x4 o = Ot[dt];
      o[0] *= aq; o[1] *= aq; o[2] *= aq; o[3] *= aq;
      bf16x8 va0 = *(const bf16x8*)(&Vt[(dt * 16 + cl) * 72 + g * 8]);
      o = __builtin_amdgcn_mfma_f32_16x16x32_bf16(va0, pb0, o, 0, 0, 0);
      bf16x8 va1 = *(const bf16x8*)(&Vt[(dt * 16 + cl) * 72 + 32 + g * 8]);
      o = __builtin_amdgcn_mfma_f32_16x16x32_bf16(va1, pb1, o, 0, 0, 0);
      Ot[dt] = o;
    }
    __builtin_amdgcn_s_setprio(0);
  }

  if (cl == 0) {
#pragma unroll
    for (int r = 0; r < 4; ++r) lsuml[w][g * 4 + r] = l_run[r];
  }
  float inv = 1.f / lsuml[w][cl];
  int orow = (i0 + w * 16 + cl) * 2 + b;
#pragma unroll
  for (int dt = 0; dt < 4; ++dt) {
    us4 o4;
    o4[0] = f2bf(Ot[dt][0] * inv);
    o4[1] = f2bf(Ot[dt][1] * inv);
    o4[2] = f2bf(Ot[dt][2] * inv);
    o4[3] = f2bf(Ot[dt][3] * inv);
    *(us4*)(&AV[(size_t)orow * 1024 + h * 64 + dt * 16 + g * 4]) = o4;
  }
}

// ---------------- GEMM 2: attn_vec @ W_o + w -> Y ----------------

__global__ __launch_bounds__(256) void k_gemm_o(const ushort_t* __restrict__ A,
                                                const ushort_t* __restrict__ B,
                                                const float* __restrict__ wsrc,
                                                float* __restrict__ Y) {
  __shared__ ushort_t Al[128 * 32], Bl[128 * 32];
  int row0 = blockIdx.x * 128, col0 = blockIdx.y * 128;
  int t = threadIdx.x, w = t >> 6, l = t & 63;
  int wr = w >> 1, wc = w & 1, g = l >> 4, cl = l & 15;
  f32x4 acc[4][4];
#pragma unroll
  for (int m = 0; m < 4; ++m)
#pragma unroll
    for (int n = 0; n < 4; ++n) acc[m][n] = (f32x4){0.f, 0.f, 0.f, 0.f};
  for (int k0 = 0; k0 < 1024; k0 += 32) {
#pragma unroll
    for (int c = 0; c < 2; ++c) {
      int u = t + 256 * c, row = u >> 2, col = (u & 3) * 8;
      async_cp16(A + (size_t)(row0 + row) * 1024 + k0 + col, &Al[u * 8]);
      async_cp16(B + (size_t)(col0 + row) * 1024 + k0 + col, &Bl[u * 8]);
    }
    __syncthreads();
    bf16x8 af[4], bfr[4];
#pragma unroll
    for (int m = 0; m < 4; ++m) af[m] = *(const bf16x8*)(&Al[(wr * 64 + m * 16 + cl) * 32 + g * 8]);
#pragma unroll
    for (int n = 0; n < 4; ++n) bfr[n] = *(const bf16x8*)(&Bl[(wc * 64 + n * 16 + cl) * 32 + g * 8]);
#pragma unroll
    for (int m = 0; m < 4; ++m)
#pragma unroll
      for (int n = 0; n < 4; ++n)
        acc[m][n] = __builtin_amdgcn_mfma_f32_16x16x32_bf16(af[m], bfr[n], acc[m][n], 0, 0, 0);
    __syncthreads();
  }
#pragma unroll
  for (int m = 0; m < 4; ++m) {
#pragma unroll
    for (int n = 0; n < 4; ++n) {
#pragma unroll
      for (int r = 0; r < 4; ++r) {
        int row = row0 + wr * 64 + m * 16 + g * 4 + r;
        int col = col0 + wc * 64 + n * 16 + cl;
        size_t idx = (size_t)row * 1024 + col;
        Y[idx] = acc[m][n][r] + wsrc[idx];
      }
    }
  }
}

// ---------------- LayerNorm ----------------

__global__ __launch_bounds__(256) void k_ln(const float* __restrict__ Y,
                                            const float* __restrict__ gg,
                                            const float* __restrict__ bb,
                                            float* __restrict__ out) {
  int row = blockIdx.x, t = threadIdx.x;
  float4 v = *(const float4*)(Y + (size_t)row * 1024 + t * 4);
  float s = v.x + v.y + v.z + v.w;
  float q = v.x * v.x + v.y * v.y + v.z * v.z + v.w * v.w;
#pragma unroll
  for (int m = 32; m >= 1; m >>= 1) {
    s += __shfl_xor(s, m);
    q += __shfl_xor(q, m);
  }
  __shared__ float ssh[4], qsh[4];
  int w = t >> 6, l = t & 63;
  if (l == 0) { ssh[w] = s; qsh[w] = q; }
  __syncthreads();
  s = ssh[0] + ssh[1] + ssh[2] + ssh[3];
  q = qsh[0] + qsh[1] + qsh[2] + qsh[3];
  float mu = s * (1.f / 1024.f);
  float var = q * (1.f / 1024.f) - mu * mu;
  float rstd = rsqrtf(var + 1e-5f);
  float4 gv = *(const float4*)(gg + t * 4);
  float4 bv = *(const float4*)(bb + t * 4);
  float4 o;
  o.x = (v.x - mu) * rstd * gv.x + bv.x;
  o.y = (v.y - mu) * rstd * gv.y + bv.y;
  o.z = (v.z - mu) * rstd * gv.z + bv.z;
  o.w = (v.w - mu) * rstd * gv.w + bv.w;
  *(float4*)(out + (size_t)row * 1024 + t * 4) = o;
}

// ---------------- launch ----------------

extern "C" void kernel_launch(void* const* d_in, const int* in_sizes, int n_in,
                              void* d_out, int out_size, void* d_ws, size_t ws_size,
                              hipStream_t stream) {
  const float* w      = (const float*)d_in[0];
  const float* r_emb  = (const float*)d_in[1];
  const float* r_w_b  = (const float*)d_in[2];
  const float* r_bias = (const float*)d_in[3];
  // d_in[4] attn_mask: implemented analytically (causal)
  const float* W_qkv  = (const float*)d_in[5];
  const float* W_o    = (const float*)d_in[6];
  const float* ln_g   = (const float*)d_in[7];
  const float* ln_b   = (const float*)d_in[8];
  float* out = (float*)d_out;
  char* ws = (char*)d_ws;

  ushort_t* X16  = (ushort_t*)(ws + 0);          //  8,388,608 B  x bf16
  ushort_t* WQ16 = (ushort_t*)(ws + 8388608);    //  6,291,456 B  Wqkv^T bf16 [3072][1024]
  ushort_t* WO16 = (ushort_t*)(ws + 14680064);   //  2,097,152 B  Wo^T bf16 [1024][1024]
  ushort_t* RE16 = (ushort_t*)(ws + 16777216);   //  4,194,304 B  r_emb bf16 [h][r][d]
  float*    RB2  = (float*)(ws + 20971520);      //    131,072 B  rbias2[h][r] (pre-scaled, base-2)
  ushort_t* QT16 = (ushort_t*)(ws + 21102592);   //  8,388,608 B  q~ bf16 [b][h][i][d] (pre-scaled, base-2)
  ushort_t* K16  = (ushort_t*)(ws + 29491200);   //  8,388,608 B  [b][h][i][d]
  ushort_t* VT16 = (ushort_t*)(ws + 37879808);   //  8,388,608 B  V^T [b][h][d][j]
  ushort_t* AV16 = (ushort_t*)(ws + 46268416);   //  8,388,608 B  attn_vec bf16 [4096][1024]
  float*    Y32  = (float*)(ws + 54657024);      // 16,777,216 B  y fp32

  k_conv_x<<<4096, 256, 0, stream>>>(w, X16);
  k_transpose_bf16<<<dim3(96, 32), dim3(32, 8), 0, stream>>>(W_qkv, WQ16, 1024, 3072);
  k_transpose_bf16<<<dim3(32, 32), dim3(32, 8), 0, stream>>>(W_o, WO16, 1024, 1024);
  k_conv_remb<<<1024, 256, 0, stream>>>(r_emb, RE16);
  k_rbias2<<<128, 256, 0, stream>>>(RE16, r_w_b, r_bias, RB2);
  k_gemm_qkv<<<dim3(32, 24), 256, 0, stream>>>(X16, WQ16, r_w_b, QT16, K16, VT16);
  k_flash<<<dim3(32, 32), 256, 0, stream>>>(QT16, K16, VT16, RE16, RB2, AV16);
  k_gemm_o<<<dim3(32, 8), 256, 0, stream>>>(AV16, WO16, w, Y32);
  k_ln<<<4096, 256, 0, stream>>>(Y32, ln_g, ln_b, out);
}